// Round 9
// baseline (399.448 us; speedup 1.0000x reference)
//
#include <hip/hip_runtime.h>

#define N_NODES 50000
#define N_EDGES 800000
#define N_GRAPHS 512
#define IN_C 128
#define HID 256
#define OUT_C 16

typedef __attribute__((ext_vector_type(8))) short short8;
typedef __attribute__((ext_vector_type(4))) float f32x4;

__device__ __forceinline__ float bf2f(unsigned short u) {
    return __uint_as_float(((unsigned int)u) << 16);
}
__device__ __forceinline__ unsigned short f2bf(float f) {
    unsigned int u = __float_as_uint(f);
    u += 0x7fff + ((u >> 16) & 1);   // RNE
    return (unsigned short)(u >> 16);
}

// Planar layout: features stored as [C/32 planes][N_NODES][32 cols] bf16.
// Each plane is 50000*64B = 3.2 MB (contiguous) -> fits one XCD's 4 MB L2.
#define PLANE_ELEMS ((long)N_NODES * 32)

// ===========================================================================
// Prep (single dispatch): x -> bf16 PLANAR, six weight transposes (K x 256
// fp32 -> 256 x K bf16), zero deg, zero sums.
// ===========================================================================
struct PrepArgs {
    const float* x;
    const float* w[6];      // K x 256 row-major; K = 128 for w[0], else 256
    ushort* xbf;            // planar [4][N][32]
    ushort* wt[6];
    int* deg;
    float* sums;
};

__global__ __launch_bounds__(256) void prep_kernel(PrepArgs a) {
    const int X4    = N_NODES * IN_C / 4;
    const int TW    = IN_C * HID;
    const int TH    = HID * HID;
    const int TBASE = X4;
    const int TEND  = TBASE + TW + 5 * TH;
    const int D4    = N_NODES / 4;
    const int DBASE = TEND;
    const int SBASE = DBASE + D4;
    const int S4    = N_GRAPHS * HID / 4;
    const long total = (long)SBASE + S4;

    long stride = (long)gridDim.x * blockDim.x;
    for (long i = (long)blockIdx.x * blockDim.x + threadIdx.x; i < total; i += stride) {
        if (i < X4) {
            float4 v = ((const float4*)a.x)[i];
            ushort4 o;
            o.x = f2bf(v.x); o.y = f2bf(v.y); o.z = f2bf(v.z); o.w = f2bf(v.w);
            long e = i * 4;
            int node = (int)(e >> 7);         // /128
            int col  = (int)(e & 127);
            long off = (long)(col >> 5) * PLANE_ELEMS + (long)node * 32 + (col & 31);
            *(ushort4*)(a.xbf + off) = o;
        } else if (i < TEND) {
            long r = i - TBASE;
            int wi, shift;
            long off;
            if (r < TW) { wi = 0; shift = 7; off = r; }
            else { r -= TW; wi = 1 + (int)(r / TH); shift = 8; off = r % TH; }
            int n = (int)(off >> shift);
            int k = (int)(off - ((long)n << shift));
            a.wt[wi][off] = f2bf(a.w[wi][(long)k * HID + n]);
        } else if (i < SBASE) {
            ((int4*)a.deg)[i - DBASE] = make_int4(0, 0, 0, 0);
        } else {
            ((float4*)a.sums)[i - SBASE] = make_float4(0.f, 0.f, 0.f, 0.f);
        }
    }
}

// ===========================================================================
// CSR build: deg+rank in one atomic pass -> scan -> XCD-sharded atomic-free
// scatter. rank[e] = position of edge e within its dst segment.
// ===========================================================================
__global__ void deg_rank_kernel(const int* __restrict__ dst, int* __restrict__ deg,
                                int* __restrict__ rank) {
    int e = blockIdx.x * blockDim.x + threadIdx.x;
    if (e < N_EDGES) rank[e] = atomicAdd(&deg[dst[e]], 1);
}

__global__ __launch_bounds__(256) void scan_block(const int* __restrict__ deg,
                                                  int* __restrict__ partial,
                                                  int* __restrict__ blockSums) {
    __shared__ int s[256];
    int t = threadIdx.x;
    int i = blockIdx.x * 256 + t;
    int v = (i < N_NODES) ? deg[i] : 0;
    s[t] = v;
    __syncthreads();
    #pragma unroll
    for (int off = 1; off < 256; off <<= 1) {
        int add = (t >= off) ? s[t - off] : 0;
        __syncthreads();
        s[t] += add;
        __syncthreads();
    }
    if (i < N_NODES) partial[i] = s[t] - v;
    if (t == 255) blockSums[blockIdx.x] = s[255];
}

__global__ __launch_bounds__(256) void add_offsets_fused(
    const int* __restrict__ partial, const int* __restrict__ blockSums,
    int* __restrict__ rowptr, int nb) {
    __shared__ int s[256];
    __shared__ int myOff;
    int t = threadIdx.x;
    int v = (t < nb) ? blockSums[t] : 0;
    s[t] = v;
    __syncthreads();
    #pragma unroll
    for (int off = 1; off < 256; off <<= 1) {
        int add = (t >= off) ? s[t - off] : 0;
        __syncthreads();
        s[t] += add;
        __syncthreads();
    }
    if (t == blockIdx.x) myOff = s[t] - v;
    __syncthreads();
    int i = blockIdx.x * 256 + t;
    if (i < N_NODES) rowptr[i] = partial[i] + myOff;
    if (i == 0) rowptr[N_NODES] = N_EDGES;
}

// XCD-sharded scatter: block b -> dst shard (b&7) on XCD (b&7); all writes to
// that shard's ~400KB srcSorted slice stay in one XCD's L2 (no cross-XCD line
// ping-pong). Atomic-free via rank[].
#define NSHARD 8
#define SHARD_SZ ((N_NODES + NSHARD - 1) / NSHARD)   // 6250
#define EDGES_PER_BLK 2048

__global__ __launch_bounds__(256) void scatter_edges_sharded(
    const int* __restrict__ src, const int* __restrict__ dst,
    const int* __restrict__ rank, const int* __restrict__ rowptr,
    int* __restrict__ srcSorted) {
    int b = blockIdx.x;
    int shard = b & 7;
    int chunk = b >> 3;
    int lo = shard * SHARD_SZ;
    int hi = lo + SHARD_SZ;
    int base = chunk * EDGES_PER_BLK + threadIdx.x;
    #pragma unroll
    for (int u = 0; u < EDGES_PER_BLK / 256; ++u) {
        int e = base + u * 256;
        if (e < N_EDGES) {
            int d = dst[e];
            if (d >= lo && d < hi)
                srcSorted[rowptr[d] + rank[e]] = src[e];
        }
    }
}

// ===========================================================================
// PERSISTENT aggregation, planar-in / row-major-out: out[n]=h[n]+sum h[src].
// Grid = 2048 blocks (8/CU, exactly the 2048-thread/CU residency cap).
// Each block grid-strides over node-blocks with stride 2048 virtual blocks;
// since 2048 % 8 == 0, b&7 (the XCD round-robin -> plane affinity) is
// invariant across iterations. Waves stay resident for the whole dispatch:
// targets the 42%-occupancy latency-bound profile of the 6256-short-block
// version (R8: FETCH already ideal at 31.5MB, L2 gathers at 25% of L2 BW).
// ===========================================================================
template <int C>
__global__ __launch_bounds__(256, 8) void gin_aggregate_persist(
    const ushort* __restrict__ hp,     // planar [C/32][N][32]
    const int* __restrict__ rowptr,
    const int* __restrict__ srcIdx,
    ushort* __restrict__ out,          // row-major [N][C]
    int nTiles)                        // node-blocks (64 nodes each) = 782
{
    constexpr int NC  = C / 32;        // 4 (C=128) or 8 (C=256)
    constexpr int PER = 8 / NC;        // XCDs per plane (2 or 1)

    int b   = blockIdx.x;              // 0..2047
    int x8  = b & 7;                   // XCD id (round-robin)
    int chunk = x8 / PER;
    int sub   = x8 & (PER - 1);
    int inner = b >> 3;                // 0..255

    int lane = threadIdx.x & 63;
    int wave = threadIdx.x >> 6;
    int grp  = lane >> 2;              // 0..15: node within wave
    int l    = lane & 3;               // 4 lanes x 8 bf16 = 32 cols

    const ushort* plane = hp + (long)chunk * PLANE_ELEMS + l * 8;

    for (int base = inner; base * PER + sub < nTiles; base += 256) {
        int nodeblk = base * PER + sub;
        int node = nodeblk * 64 + wave * 16 + grp;
        if (node >= N_NODES) continue;

        float acc[8];
        {
            short8 sv = *(const short8*)(plane + (long)node * 32);
            #pragma unroll
            for (int v = 0; v < 8; ++v) acc[v] = bf2f((unsigned short)sv[v]);
        }

        int beg = rowptr[node], end = rowptr[node + 1];
        int k = beg;
        for (; k + 8 <= end; k += 8) {
            int si[8];
            #pragma unroll
            for (int u = 0; u < 8; ++u) si[u] = srcIdx[k + u];
            short8 r[8];
            #pragma unroll
            for (int u = 0; u < 8; ++u) r[u] = *(const short8*)(plane + (long)si[u] * 32);
            #pragma unroll
            for (int u = 0; u < 8; ++u)
                #pragma unroll
                for (int v = 0; v < 8; ++v) acc[v] += bf2f((unsigned short)r[u][v]);
        }
        for (; k + 2 <= end; k += 2) {
            int si0 = srcIdx[k], si1 = srcIdx[k + 1];
            short8 r0 = *(const short8*)(plane + (long)si0 * 32);
            short8 r1 = *(const short8*)(plane + (long)si1 * 32);
            #pragma unroll
            for (int v = 0; v < 8; ++v) acc[v] += bf2f((unsigned short)r0[v]);
            #pragma unroll
            for (int v = 0; v < 8; ++v) acc[v] += bf2f((unsigned short)r1[v]);
        }
        if (k < end) {
            short8 r = *(const short8*)(plane + (long)srcIdx[k] * 32);
            #pragma unroll
            for (int v = 0; v < 8; ++v) acc[v] += bf2f((unsigned short)r[v]);
        }

        short8 o;
        #pragma unroll
        for (int v = 0; v < 8; ++v) o[v] = (short)f2bf(acc[v]);
        __builtin_nontemporal_store(o, (short8*)(out + (long)node * C + chunk * 32 + l * 8));
    }
}

// ===========================================================================
// PERSISTENT fused 2-layer MLP (round-7, kept: removed gin_mlp from top-5).
// Grid = 256 blocks (1/CU); W1+W2 slices live in registers across all tiles.
// ===========================================================================
template <int K1, bool FUSE_POOL>
__global__ __launch_bounds__(512, 2) void gin_mlp_persist(
    const ushort* __restrict__ A,
    const ushort* __restrict__ w1t,
    const float* __restrict__ b1,
    const ushort* __restrict__ w2t,
    const float* __restrict__ b2,
    ushort* __restrict__ out,          // planar [8][N][32]
    const int* __restrict__ batch,
    float* __restrict__ sums,
    int M, int nTiles, int nPers)
{
    constexpr int NCH1 = K1 / 8;        // 16 or 32
    constexpr int NSLOT1 = 64 * NCH1;   // 1024 or 2048
    constexpr int NS1 = K1 / 32;        // 4 or 8
    constexpr int PFN = NSLOT1 / 512;   // 2 or 4 short8 per thread per stage

    __shared__ short LsA[NSLOT1 * 8];   // 16 KB (K=128) / 32 KB (K=256)
    __shared__ short LsH[2048 * 8];     // 32 KB

    int t = threadIdx.x;
    int lane = t & 63;
    int wv = t >> 6;                    // 0..7
    int quad = lane >> 4;
    int l15 = lane & 15;
    int swz = l15 & 7;
    int col0 = wv * 32;

    // ---- Preload W1 + W2 slices and biases into registers (once) ----
    short8 w1r[NS1 * 2];
    #pragma unroll
    for (int s = 0; s < NS1; ++s)
        #pragma unroll
        for (int j = 0; j < 2; ++j)
            w1r[s * 2 + j] = *(const short8*)(w1t + (long)(col0 + j * 16 + l15) * K1 + s * 32 + quad * 8);
    short8 w2r[16];
    #pragma unroll
    for (int s = 0; s < 8; ++s)
        #pragma unroll
        for (int j = 0; j < 2; ++j)
            w2r[s * 2 + j] = *(const short8*)(w2t + (long)(col0 + j * 16 + l15) * 256 + s * 32 + quad * 8);
    float bv1[2], bv2[2];
    #pragma unroll
    for (int j = 0; j < 2; ++j) {
        bv1[j] = b1[col0 + j * 16 + l15];
        bv2[j] = b2[col0 + j * 16 + l15];
    }

    // ---- Contiguous tile range for this block ----
    int t0 = (int)(((long)blockIdx.x * nTiles) / nPers);
    int t1 = (int)(((long)(blockIdx.x + 1) * nTiles) / nPers);

    const f32x4 zero = {0.f, 0.f, 0.f, 0.f};

    for (int ti = t0; ti < t1; ++ti) {
        int row0 = ti * 64;

        // ---- Stage A tile (64 x K1, source-side swizzle) into LsA ----
        #pragma unroll
        for (int c = 0; c < PFN; ++c) {
            int s = c * 512 + t;
            int row = s / NCH1;
            int kcs = s & (NCH1 - 1);
            int kc = kcs ^ (row & 7);
            int grow = row0 + row;
            if (grow >= M) grow = M - 1;
            *(short8*)&LsA[s * 8] = *(const short8*)(A + (long)grow * K1 + kc * 8);
        }
        __syncthreads();

        // ---- Layer 1: LDS + registers only ----
        f32x4 acc[4][2];
        #pragma unroll
        for (int i = 0; i < 4; ++i)
            #pragma unroll
            for (int j = 0; j < 2; ++j) acc[i][j] = zero;

        #pragma unroll
        for (int s = 0; s < NS1; ++s) {
            #pragma unroll
            for (int i = 0; i < 4; ++i) {
                int row = i * 16 + l15;
                int slot = row * NCH1 + ((s * 4 + quad) ^ swz);
                short8 a = *(const short8*)&LsA[slot * 8];
                acc[i][0] = __builtin_amdgcn_mfma_f32_16x16x32_bf16(a, w1r[s * 2 + 0], acc[i][0], 0, 0, 0);
                acc[i][1] = __builtin_amdgcn_mfma_f32_16x16x32_bf16(a, w1r[s * 2 + 1], acc[i][1], 0, 0, 0);
            }
        }
        __syncthreads();

        // ---- H = relu(acc + b1) -> LsH (swizzled 64 x 256 bf16) ----
        #pragma unroll
        for (int i = 0; i < 4; ++i)
            #pragma unroll
            for (int j = 0; j < 2; ++j) {
                int col = col0 + j * 16 + l15;
                int kc2 = col >> 3, sub = col & 7;
                #pragma unroll
                for (int r = 0; r < 4; ++r) {
                    int row = i * 16 + quad * 4 + r;
                    int slot = row * 32 + (kc2 ^ (row & 7));
                    float o = fmaxf(acc[i][j][r] + bv1[j], 0.f);
                    LsH[slot * 8 + sub] = (short)f2bf(o);
                }
            }
        __syncthreads();

        // ---- Layer 2: LDS + registers only ----
        #pragma unroll
        for (int i = 0; i < 4; ++i)
            #pragma unroll
            for (int j = 0; j < 2; ++j) acc[i][j] = zero;

        #pragma unroll
        for (int s = 0; s < 8; ++s) {
            #pragma unroll
            for (int i = 0; i < 4; ++i) {
                int row = i * 16 + l15;
                int slot = row * 32 + ((s * 4 + quad) ^ swz);
                short8 a = *(const short8*)&LsH[slot * 8];
                acc[i][0] = __builtin_amdgcn_mfma_f32_16x16x32_bf16(a, w2r[s * 2 + 0], acc[i][0], 0, 0, 0);
                acc[i][1] = __builtin_amdgcn_mfma_f32_16x16x32_bf16(a, w2r[s * 2 + 1], acc[i][1], 0, 0, 0);
            }
        }

        // ---- Epilogue ----
        if constexpr (!FUSE_POOL) {
            #pragma unroll
            for (int i = 0; i < 4; ++i)
                #pragma unroll
                for (int r = 0; r < 4; ++r) {
                    int grow = row0 + i * 16 + quad * 4 + r;
                    if (grow >= M) continue;
                    #pragma unroll
                    for (int j = 0; j < 2; ++j) {
                        int col = col0 + j * 16 + l15;
                        float o = fmaxf(acc[i][j][r] + bv2[j], 0.f);
                        out[(long)(col >> 5) * PLANE_ELEMS + (long)grow * 32 + (col & 31)] = f2bf(o);
                    }
                }
        } else {
            float pacc[2];
            #pragma unroll
            for (int j = 0; j < 2; ++j) pacc[j] = 0.f;
            int cur = -1;
            #pragma unroll
            for (int i = 0; i < 4; ++i) {
                #pragma unroll
                for (int r = 0; r < 4; ++r) {
                    int row = row0 + i * 16 + quad * 4 + r;
                    if (row >= M) continue;
                    int g = batch[row];
                    if (g != cur) {
                        if (cur >= 0) {
                            #pragma unroll
                            for (int j = 0; j < 2; ++j)
                                atomicAdd(&sums[(long)cur * 256 + col0 + j * 16 + l15], pacc[j]);
                        }
                        cur = g;
                        #pragma unroll
                        for (int j = 0; j < 2; ++j) pacc[j] = 0.f;
                    }
                    #pragma unroll
                    for (int j = 0; j < 2; ++j)
                        pacc[j] += fmaxf(acc[i][j][r] + bv2[j], 0.f);
                }
            }
            if (cur >= 0) {
                #pragma unroll
                for (int j = 0; j < 2; ++j)
                    atomicAdd(&sums[(long)cur * 256 + col0 + j * 16 + l15], pacc[j]);
            }
        }
    }
}

// ===========================================================================
// Head MLP (fp32): one block per graph; count via binary search on batch.
// ===========================================================================
__global__ __launch_bounds__(256) void final_mlp_kernel(
    const float* __restrict__ sums, const int* __restrict__ batch,
    const float* __restrict__ w1, const float* __restrict__ b1,
    const float* __restrict__ w2, const float* __restrict__ b2,
    float* __restrict__ out) {
    __shared__ float row[HID];
    __shared__ float hid[HID];
    __shared__ int cntS;
    int g = blockIdx.x;
    int t = threadIdx.x;
    if (t == 0) {
        int lo = 0, hi = N_NODES;
        while (lo < hi) { int m = (lo + hi) >> 1; if (batch[m] < g) lo = m + 1; else hi = m; }
        int lo2 = lo, hi2 = N_NODES;
        while (lo2 < hi2) { int m = (lo2 + hi2) >> 1; if (batch[m] < g + 1) lo2 = m + 1; else hi2 = m; }
        cntS = lo2 - lo;
    }
    __syncthreads();
    float cnt = fmaxf((float)cntS, 1.0f);
    row[t] = sums[(long)g * HID + t] / cnt;
    __syncthreads();
    float acc = b1[t];
    for (int k = 0; k < HID; ++k) acc += row[k] * w1[k * HID + t];
    hid[t] = fmaxf(acc, 0.f);
    __syncthreads();
    if (t < OUT_C) {
        float o = b2[t];
        for (int k = 0; k < HID; ++k) o += hid[k] * w2[k * OUT_C + t];
        out[(long)g * OUT_C + t] = o;
    }
}

// ---------------------------------------------------------------------------
extern "C" void kernel_launch(void* const* d_in, const int* in_sizes, int n_in,
                              void* d_out, int out_size, void* d_ws, size_t ws_size,
                              hipStream_t stream) {
    const float* x     = (const float*)d_in[0];
    const int*   ei    = (const int*)d_in[1];
    const int*   batch = (const int*)d_in[2];
    const int*   src   = ei;
    const int*   dst   = ei + N_EDGES;

    const float* c_w1[3] = { (const float*)d_in[3],  (const float*)d_in[7],  (const float*)d_in[11] };
    const float* c_b1[3] = { (const float*)d_in[4],  (const float*)d_in[8],  (const float*)d_in[12] };
    const float* c_w2[3] = { (const float*)d_in[5],  (const float*)d_in[9],  (const float*)d_in[13] };
    const float* c_b2[3] = { (const float*)d_in[6],  (const float*)d_in[10], (const float*)d_in[14] };
    const float* out_w1 = (const float*)d_in[15];
    const float* out_b1 = (const float*)d_in[16];
    const float* out_w2 = (const float*)d_in[17];
    const float* out_b2 = (const float*)d_in[18];

    // ---- Workspace layout (16B aligned) ----
    char* p = (char*)d_ws;
    auto alloc = [&](size_t bytes) {
        char* r = p;
        p += (bytes + 15) & ~(size_t)15;
        return r;
    };
    ushort* xbf  = (ushort*)alloc((size_t)N_NODES * IN_C * 2);   // planar [4][N][32]
    ushort* bufA = (ushort*)alloc((size_t)N_NODES * HID * 2);    // planar [8][N][32]
    ushort* bufB = (ushort*)alloc((size_t)N_NODES * HID * 2);    // row-major agg output
    ushort* wt[6];
    wt[0] = (ushort*)alloc((size_t)IN_C * HID * 2);
    for (int i = 1; i < 6; ++i) wt[i] = (ushort*)alloc((size_t)HID * HID * 2);
    float* sums   = (float*)alloc((size_t)N_GRAPHS * HID * 4);
    int* deg       = (int*)alloc((size_t)N_NODES * 4);
    int* rowptr    = (int*)alloc((size_t)(N_NODES + 1) * 4);
    int* blockSums = (int*)alloc(256 * 4);
    int* rank      = (int*)alloc((size_t)N_EDGES * 4);
    int* srcSorted = (int*)alloc((size_t)N_EDGES * 4);

    const int nb = (N_NODES + 255) / 256;

    // ---- Prep: one dispatch for casts + transposes + zeroing ----
    {
        PrepArgs a;
        a.x = x;
        a.w[0] = c_w1[0]; a.w[1] = c_w2[0];
        a.w[2] = c_w1[1]; a.w[3] = c_w2[1];
        a.w[4] = c_w1[2]; a.w[5] = c_w2[2];
        a.xbf = xbf;
        for (int i = 0; i < 6; ++i) a.wt[i] = wt[i];
        a.deg = deg;
        a.sums = sums;
        prep_kernel<<<2048, 256, 0, stream>>>(a);
    }

    // ---- Build CSR by dst: deg+rank -> scan -> sharded atomic-free scatter ----
    deg_rank_kernel<<<(N_EDGES + 255) / 256, 256, 0, stream>>>(dst, deg, rank);
    scan_block<<<nb, 256, 0, stream>>>(deg, rowptr, blockSums);
    add_offsets_fused<<<nb, 256, 0, stream>>>(rowptr, blockSums, rowptr, nb);
    {
        const int chunks = (N_EDGES + EDGES_PER_BLK - 1) / EDGES_PER_BLK;  // 391
        scatter_edges_sharded<<<chunks * NSHARD, 256, 0, stream>>>(src, dst, rank, rowptr, srcSorted);
    }

    const int nodeBlks = (N_NODES + 63) / 64;        // 782 (even, needed for PER=2)
    const int AGG_GRID = 2048;                       // 8 blocks/CU, persistent
    const int NPERS    = 256;                        // persistent MLP grid (1/CU)

    // ---- Layer 0 (C_in = 128) ----
    gin_aggregate_persist<IN_C><<<AGG_GRID, 256, 0, stream>>>(xbf, rowptr, srcSorted, bufB, nodeBlks);
    gin_mlp_persist<IN_C, false><<<NPERS, 512, 0, stream>>>(bufB, wt[0], c_b1[0], wt[1], c_b2[0],
                                                            bufA, batch, sums, N_NODES, nodeBlks, NPERS);

    // ---- Layer 1 (C = 256) ----
    gin_aggregate_persist<HID><<<AGG_GRID, 256, 0, stream>>>(bufA, rowptr, srcSorted, bufB, nodeBlks);
    gin_mlp_persist<HID, false><<<NPERS, 512, 0, stream>>>(bufB, wt[2], c_b1[1], wt[3], c_b2[1],
                                                           bufA, batch, sums, N_NODES, nodeBlks, NPERS);

    // ---- Layer 2 (C = 256) with fused global mean-pool accumulation ----
    gin_aggregate_persist<HID><<<AGG_GRID, 256, 0, stream>>>(bufA, rowptr, srcSorted, bufB, nodeBlks);
    gin_mlp_persist<HID, true><<<NPERS, 512, 0, stream>>>(bufB, wt[4], c_b1[2], wt[5], c_b2[2],
                                                          bufA, batch, sums, N_NODES, nodeBlks, NPERS);

    // ---- Head MLP ----
    final_mlp_kernel<<<N_GRAPHS, 256, 0, stream>>>(sums, batch, out_w1, out_b1,
                                                   out_w2, out_b2, (float*)d_out);
}

// Round 10
// 396.690 us; speedup vs baseline: 1.0070x; 1.0070x over previous
//
#include <hip/hip_runtime.h>

#define N_NODES 50000
#define N_EDGES 800000
#define N_GRAPHS 512
#define IN_C 128
#define HID 256
#define OUT_C 16

typedef __attribute__((ext_vector_type(8))) short short8;
typedef __attribute__((ext_vector_type(4))) float f32x4;

__device__ __forceinline__ float bf2f(unsigned short u) {
    return __uint_as_float(((unsigned int)u) << 16);
}
__device__ __forceinline__ unsigned short f2bf(float f) {
    unsigned int u = __float_as_uint(f);
    u += 0x7fff + ((u >> 16) & 1);   // RNE
    return (unsigned short)(u >> 16);
}

// Planar layout: features stored as [C/32 planes][N_NODES][32 cols] bf16.
// Each plane is 50000*64B = 3.2 MB (contiguous) -> fits one XCD's 4 MB L2.
#define PLANE_ELEMS ((long)N_NODES * 32)

// ===========================================================================
// Prep (single dispatch): x -> bf16 PLANAR, six weight transposes (K x 256
// fp32 -> 256 x K bf16), zero deg, zero sums.
// ===========================================================================
struct PrepArgs {
    const float* x;
    const float* w[6];      // K x 256 row-major; K = 128 for w[0], else 256
    ushort* xbf;            // planar [4][N][32]
    ushort* wt[6];
    int* deg;
    float* sums;
};

__global__ __launch_bounds__(256) void prep_kernel(PrepArgs a) {
    const int X4    = N_NODES * IN_C / 4;
    const int TW    = IN_C * HID;
    const int TH    = HID * HID;
    const int TBASE = X4;
    const int TEND  = TBASE + TW + 5 * TH;
    const int D4    = N_NODES / 4;
    const int DBASE = TEND;
    const int SBASE = DBASE + D4;
    const int S4    = N_GRAPHS * HID / 4;
    const long total = (long)SBASE + S4;

    long stride = (long)gridDim.x * blockDim.x;
    for (long i = (long)blockIdx.x * blockDim.x + threadIdx.x; i < total; i += stride) {
        if (i < X4) {
            float4 v = ((const float4*)a.x)[i];
            ushort4 o;
            o.x = f2bf(v.x); o.y = f2bf(v.y); o.z = f2bf(v.z); o.w = f2bf(v.w);
            long e = i * 4;
            int node = (int)(e >> 7);         // /128
            int col  = (int)(e & 127);
            long off = (long)(col >> 5) * PLANE_ELEMS + (long)node * 32 + (col & 31);
            *(ushort4*)(a.xbf + off) = o;
        } else if (i < TEND) {
            long r = i - TBASE;
            int wi, shift;
            long off;
            if (r < TW) { wi = 0; shift = 7; off = r; }
            else { r -= TW; wi = 1 + (int)(r / TH); shift = 8; off = r % TH; }
            int n = (int)(off >> shift);
            int k = (int)(off - ((long)n << shift));
            a.wt[wi][off] = f2bf(a.w[wi][(long)k * HID + n]);
        } else if (i < SBASE) {
            ((int4*)a.deg)[i - DBASE] = make_int4(0, 0, 0, 0);
        } else {
            ((float4*)a.sums)[i - SBASE] = make_float4(0.f, 0.f, 0.f, 0.f);
        }
    }
}

// ===========================================================================
// CSR build: deg+rank in one atomic pass -> scan -> XCD-sharded atomic-free
// scatter. rank[e] = position of edge e within its dst segment.
// ===========================================================================
__global__ void deg_rank_kernel(const int* __restrict__ dst, int* __restrict__ deg,
                                int* __restrict__ rank) {
    int e = blockIdx.x * blockDim.x + threadIdx.x;
    if (e < N_EDGES) rank[e] = atomicAdd(&deg[dst[e]], 1);
}

__global__ __launch_bounds__(256) void scan_block(const int* __restrict__ deg,
                                                  int* __restrict__ partial,
                                                  int* __restrict__ blockSums) {
    __shared__ int s[256];
    int t = threadIdx.x;
    int i = blockIdx.x * 256 + t;
    int v = (i < N_NODES) ? deg[i] : 0;
    s[t] = v;
    __syncthreads();
    #pragma unroll
    for (int off = 1; off < 256; off <<= 1) {
        int add = (t >= off) ? s[t - off] : 0;
        __syncthreads();
        s[t] += add;
        __syncthreads();
    }
    if (i < N_NODES) partial[i] = s[t] - v;
    if (t == 255) blockSums[blockIdx.x] = s[255];
}

__global__ __launch_bounds__(256) void add_offsets_fused(
    const int* __restrict__ partial, const int* __restrict__ blockSums,
    int* __restrict__ rowptr, int nb) {
    __shared__ int s[256];
    __shared__ int myOff;
    int t = threadIdx.x;
    int v = (t < nb) ? blockSums[t] : 0;
    s[t] = v;
    __syncthreads();
    #pragma unroll
    for (int off = 1; off < 256; off <<= 1) {
        int add = (t >= off) ? s[t - off] : 0;
        __syncthreads();
        s[t] += add;
        __syncthreads();
    }
    if (t == blockIdx.x) myOff = s[t] - v;
    __syncthreads();
    int i = blockIdx.x * 256 + t;
    if (i < N_NODES) rowptr[i] = partial[i] + myOff;
    if (i == 0) rowptr[N_NODES] = N_EDGES;
}

// XCD-sharded scatter: block b -> dst shard (b&7) on XCD (b&7); all writes to
// that shard's ~400KB srcSorted slice stay in one XCD's L2 (no cross-XCD line
// ping-pong). Atomic-free via rank[].
#define NSHARD 8
#define SHARD_SZ ((N_NODES + NSHARD - 1) / NSHARD)   // 6250
#define EDGES_PER_BLK 2048

__global__ __launch_bounds__(256) void scatter_edges_sharded(
    const int* __restrict__ src, const int* __restrict__ dst,
    const int* __restrict__ rank, const int* __restrict__ rowptr,
    int* __restrict__ srcSorted) {
    int b = blockIdx.x;
    int shard = b & 7;
    int chunk = b >> 3;
    int lo = shard * SHARD_SZ;
    int hi = lo + SHARD_SZ;
    int base = chunk * EDGES_PER_BLK + threadIdx.x;
    #pragma unroll
    for (int u = 0; u < EDGES_PER_BLK / 256; ++u) {
        int e = base + u * 256;
        if (e < N_EDGES) {
            int d = dst[e];
            if (d >= lo && d < hi)
                srcSorted[rowptr[d] + rank[e]] = src[e];
        }
    }
}

// ===========================================================================
// Aggregation (R8 best-measured form: 47.9us, FETCH 31.5MB): planar-in /
// row-major-out. Cached index loads, nt output stores.
// ===========================================================================
template <int C>
__global__ __launch_bounds__(256) void gin_aggregate_planar(
    const ushort* __restrict__ hp,     // planar [C/32][N][32]
    const int* __restrict__ rowptr,
    const int* __restrict__ srcIdx,
    ushort* __restrict__ out)          // row-major [N][C]
{
    constexpr int NC  = C / 32;        // 4 (C=128) or 8 (C=256)
    constexpr int PER = 8 / NC;        // XCDs per plane (2 or 1)

    int b  = blockIdx.x;
    int x8 = b & 7;                    // presumed XCD id (round-robin)
    int chunk   = x8 / PER;
    int nodeblk = (b >> 3) * PER + (x8 & (PER - 1));

    int lane = threadIdx.x & 63;
    int wave = threadIdx.x >> 6;
    int grp  = lane >> 2;              // 0..15: node within wave
    int l    = lane & 3;               // 4 lanes x 8 bf16 = 32 cols
    int node = nodeblk * 64 + wave * 16 + grp;
    if (node >= N_NODES) return;

    const ushort* plane = hp + (long)chunk * PLANE_ELEMS + l * 8;

    float acc[8];
    {
        short8 sv = *(const short8*)(plane + (long)node * 32);
        #pragma unroll
        for (int v = 0; v < 8; ++v) acc[v] = bf2f((unsigned short)sv[v]);
    }

    int beg = rowptr[node], end = rowptr[node + 1];
    int k = beg;
    for (; k + 8 <= end; k += 8) {
        int si[8];
        #pragma unroll
        for (int u = 0; u < 8; ++u) si[u] = srcIdx[k + u];
        short8 r[8];
        #pragma unroll
        for (int u = 0; u < 8; ++u) r[u] = *(const short8*)(plane + (long)si[u] * 32);
        #pragma unroll
        for (int u = 0; u < 8; ++u)
            #pragma unroll
            for (int v = 0; v < 8; ++v) acc[v] += bf2f((unsigned short)r[u][v]);
    }
    for (; k + 2 <= end; k += 2) {
        int si0 = srcIdx[k], si1 = srcIdx[k + 1];
        short8 r0 = *(const short8*)(plane + (long)si0 * 32);
        short8 r1 = *(const short8*)(plane + (long)si1 * 32);
        #pragma unroll
        for (int v = 0; v < 8; ++v) acc[v] += bf2f((unsigned short)r0[v]);
        #pragma unroll
        for (int v = 0; v < 8; ++v) acc[v] += bf2f((unsigned short)r1[v]);
    }
    if (k < end) {
        short8 r = *(const short8*)(plane + (long)srcIdx[k] * 32);
        #pragma unroll
        for (int v = 0; v < 8; ++v) acc[v] += bf2f((unsigned short)r[v]);
    }

    short8 o;
    #pragma unroll
    for (int v = 0; v < 8; ++v) o[v] = (short)f2bf(acc[v]);
    __builtin_nontemporal_store(o, (short8*)(out + (long)node * C + chunk * 32 + l * 8));
}

// ===========================================================================
// PERSISTENT fused 2-layer MLP, v2:
//  - W1/W2 slices PINNED in registers via asm ("+v") after preload. (R9 PMC
//    showed VGPR=60: the compiler had sunk the weight loads back into the
//    K-loops -> per-MFMA global loads -> MfmaUtil 9%. launch_bounds(512,2)
//    gives a 256-VGPR cap; est. use ~200.)
//  - T14 async-stage: next tile's A-loads issued into registers BEFORE the
//    barriers; regs->LsA at top of next iteration. Staging latency hides
//    under the current tile's MFMA + epilogue.
// Barrier safety: LsA write (top of iter) is ordered after prev iter's LsA
// reads by prev B2; LsH write (after B2) is ordered after prev L2-loop reads
// by B1+B2. 3 barriers/tile.
// ===========================================================================
template <int K1, bool FUSE_POOL>
__global__ __launch_bounds__(512, 2) void gin_mlp_persist(
    const ushort* __restrict__ A,
    const ushort* __restrict__ w1t,
    const float* __restrict__ b1,
    const ushort* __restrict__ w2t,
    const float* __restrict__ b2,
    ushort* __restrict__ out,          // planar [8][N][32]
    const int* __restrict__ batch,
    float* __restrict__ sums,
    int M, int nTiles, int nPers)
{
    constexpr int NCH1 = K1 / 8;        // 16 or 32
    constexpr int NSLOT1 = 64 * NCH1;   // 1024 or 2048
    constexpr int NS1 = K1 / 32;        // 4 or 8
    constexpr int PFN = NSLOT1 / 512;   // 2 or 4 short8 per thread per stage

    __shared__ short LsA[NSLOT1 * 8];   // 16 KB (K=128) / 32 KB (K=256)
    __shared__ short LsH[2048 * 8];     // 32 KB

    int t = threadIdx.x;
    int lane = t & 63;
    int wv = t >> 6;                    // 0..7
    int quad = lane >> 4;
    int l15 = lane & 15;
    int swz = l15 & 7;
    int col0 = wv * 32;

    // ---- Preload W1 + W2 slices and biases into registers (once), pinned ----
    short8 w1r[NS1 * 2];
    #pragma unroll
    for (int s = 0; s < NS1; ++s)
        #pragma unroll
        for (int j = 0; j < 2; ++j)
            w1r[s * 2 + j] = *(const short8*)(w1t + (long)(col0 + j * 16 + l15) * K1 + s * 32 + quad * 8);
    short8 w2r[16];
    #pragma unroll
    for (int s = 0; s < 8; ++s)
        #pragma unroll
        for (int j = 0; j < 2; ++j)
            w2r[s * 2 + j] = *(const short8*)(w2t + (long)(col0 + j * 16 + l15) * 256 + s * 32 + quad * 8);
    #pragma unroll
    for (int i = 0; i < NS1 * 2; ++i) asm volatile("" : "+v"(w1r[i]));
    #pragma unroll
    for (int i = 0; i < 16; ++i) asm volatile("" : "+v"(w2r[i]));

    float bv1[2], bv2[2];
    #pragma unroll
    for (int j = 0; j < 2; ++j) {
        bv1[j] = b1[col0 + j * 16 + l15];
        bv2[j] = b2[col0 + j * 16 + l15];
    }

    // ---- Per-thread staging geometry (tile-invariant) ----
    int prow[PFN], pkcB[PFN];
    #pragma unroll
    for (int c = 0; c < PFN; ++c) {
        int s = c * 512 + t;
        prow[c] = s / NCH1;
        int kcs = s & (NCH1 - 1);
        pkcB[c] = (kcs ^ (prow[c] & 7)) * 8;
    }

    // ---- Contiguous tile range for this block ----
    int t0 = (int)(((long)blockIdx.x * nTiles) / nPers);
    int t1 = (int)(((long)(blockIdx.x + 1) * nTiles) / nPers);
    if (t0 >= t1) return;

    const f32x4 zero = {0.f, 0.f, 0.f, 0.f};

    short8 pf[PFN];
    // prefetch first tile
    {
        int row0 = t0 * 64;
        #pragma unroll
        for (int c = 0; c < PFN; ++c) {
            int grow = row0 + prow[c];
            if (grow >= M) grow = M - 1;
            pf[c] = *(const short8*)(A + (long)grow * K1 + pkcB[c]);
        }
    }

    for (int ti = t0; ti < t1; ++ti) {
        int row0 = ti * 64;

        // ---- Commit prefetched A tile to LsA; issue next tile's loads ----
        #pragma unroll
        for (int c = 0; c < PFN; ++c)
            *(short8*)&LsA[(c * 512 + t) * 8] = pf[c];
        if (ti + 1 < t1) {
            int nrow0 = (ti + 1) * 64;
            #pragma unroll
            for (int c = 0; c < PFN; ++c) {
                int grow = nrow0 + prow[c];
                if (grow >= M) grow = M - 1;
                pf[c] = *(const short8*)(A + (long)grow * K1 + pkcB[c]);
            }
        }
        __syncthreads();                       // B1

        // ---- Layer 1: LDS + registers only ----
        f32x4 acc[4][2];
        #pragma unroll
        for (int i = 0; i < 4; ++i)
            #pragma unroll
            for (int j = 0; j < 2; ++j) acc[i][j] = zero;

        #pragma unroll
        for (int s = 0; s < NS1; ++s) {
            #pragma unroll
            for (int i = 0; i < 4; ++i) {
                int row = i * 16 + l15;
                int slot = row * NCH1 + ((s * 4 + quad) ^ swz);
                short8 a = *(const short8*)&LsA[slot * 8];
                acc[i][0] = __builtin_amdgcn_mfma_f32_16x16x32_bf16(a, w1r[s * 2 + 0], acc[i][0], 0, 0, 0);
                acc[i][1] = __builtin_amdgcn_mfma_f32_16x16x32_bf16(a, w1r[s * 2 + 1], acc[i][1], 0, 0, 0);
            }
        }
        __syncthreads();                       // B2

        // ---- H = relu(acc + b1) -> LsH (swizzled 64 x 256 bf16) ----
        #pragma unroll
        for (int i = 0; i < 4; ++i)
            #pragma unroll
            for (int j = 0; j < 2; ++j) {
                int col = col0 + j * 16 + l15;
                int kc2 = col >> 3, sub = col & 7;
                #pragma unroll
                for (int r = 0; r < 4; ++r) {
                    int row = i * 16 + quad * 4 + r;
                    int slot = row * 32 + (kc2 ^ (row & 7));
                    float o = fmaxf(acc[i][j][r] + bv1[j], 0.f);
                    LsH[slot * 8 + sub] = (short)f2bf(o);
                }
            }
        __syncthreads();                       // B3

        // ---- Layer 2: LDS + registers only ----
        #pragma unroll
        for (int i = 0; i < 4; ++i)
            #pragma unroll
            for (int j = 0; j < 2; ++j) acc[i][j] = zero;

        #pragma unroll
        for (int s = 0; s < 8; ++s) {
            #pragma unroll
            for (int i = 0; i < 4; ++i) {
                int row = i * 16 + l15;
                int slot = row * 32 + ((s * 4 + quad) ^ swz);
                short8 a = *(const short8*)&LsH[slot * 8];
                acc[i][0] = __builtin_amdgcn_mfma_f32_16x16x32_bf16(a, w2r[s * 2 + 0], acc[i][0], 0, 0, 0);
                acc[i][1] = __builtin_amdgcn_mfma_f32_16x16x32_bf16(a, w2r[s * 2 + 1], acc[i][1], 0, 0, 0);
            }
        }

        // ---- Epilogue ----
        if constexpr (!FUSE_POOL) {
            #pragma unroll
            for (int i = 0; i < 4; ++i)
                #pragma unroll
                for (int r = 0; r < 4; ++r) {
                    int grow = row0 + i * 16 + quad * 4 + r;
                    if (grow >= M) continue;
                    #pragma unroll
                    for (int j = 0; j < 2; ++j) {
                        int col = col0 + j * 16 + l15;
                        float o = fmaxf(acc[i][j][r] + bv2[j], 0.f);
                        out[(long)(col >> 5) * PLANE_ELEMS + (long)grow * 32 + (col & 31)] = f2bf(o);
                    }
                }
        } else {
            float pacc[2];
            #pragma unroll
            for (int j = 0; j < 2; ++j) pacc[j] = 0.f;
            int cur = -1;
            #pragma unroll
            for (int i = 0; i < 4; ++i) {
                #pragma unroll
                for (int r = 0; r < 4; ++r) {
                    int row = row0 + i * 16 + quad * 4 + r;
                    if (row >= M) continue;
                    int g = batch[row];
                    if (g != cur) {
                        if (cur >= 0) {
                            #pragma unroll
                            for (int j = 0; j < 2; ++j)
                                atomicAdd(&sums[(long)cur * 256 + col0 + j * 16 + l15], pacc[j]);
                        }
                        cur = g;
                        #pragma unroll
                        for (int j = 0; j < 2; ++j) pacc[j] = 0.f;
                    }
                    #pragma unroll
                    for (int j = 0; j < 2; ++j)
                        pacc[j] += fmaxf(acc[i][j][r] + bv2[j], 0.f);
                }
            }
            if (cur >= 0) {
                #pragma unroll
                for (int j = 0; j < 2; ++j)
                    atomicAdd(&sums[(long)cur * 256 + col0 + j * 16 + l15], pacc[j]);
            }
        }
    }
}

// ===========================================================================
// Head MLP (fp32): one block per graph; count via binary search on batch.
// ===========================================================================
__global__ __launch_bounds__(256) void final_mlp_kernel(
    const float* __restrict__ sums, const int* __restrict__ batch,
    const float* __restrict__ w1, const float* __restrict__ b1,
    const float* __restrict__ w2, const float* __restrict__ b2,
    float* __restrict__ out) {
    __shared__ float row[HID];
    __shared__ float hid[HID];
    __shared__ int cntS;
    int g = blockIdx.x;
    int t = threadIdx.x;
    if (t == 0) {
        int lo = 0, hi = N_NODES;
        while (lo < hi) { int m = (lo + hi) >> 1; if (batch[m] < g) lo = m + 1; else hi = m; }
        int lo2 = lo, hi2 = N_NODES;
        while (lo2 < hi2) { int m = (lo2 + hi2) >> 1; if (batch[m] < g + 1) lo2 = m + 1; else hi2 = m; }
        cntS = lo2 - lo;
    }
    __syncthreads();
    float cnt = fmaxf((float)cntS, 1.0f);
    row[t] = sums[(long)g * HID + t] / cnt;
    __syncthreads();
    float acc = b1[t];
    for (int k = 0; k < HID; ++k) acc += row[k] * w1[k * HID + t];
    hid[t] = fmaxf(acc, 0.f);
    __syncthreads();
    if (t < OUT_C) {
        float o = b2[t];
        for (int k = 0; k < HID; ++k) o += hid[k] * w2[k * OUT_C + t];
        out[(long)g * OUT_C + t] = o;
    }
}

// ---------------------------------------------------------------------------
extern "C" void kernel_launch(void* const* d_in, const int* in_sizes, int n_in,
                              void* d_out, int out_size, void* d_ws, size_t ws_size,
                              hipStream_t stream) {
    const float* x     = (const float*)d_in[0];
    const int*   ei    = (const int*)d_in[1];
    const int*   batch = (const int*)d_in[2];
    const int*   src   = ei;
    const int*   dst   = ei + N_EDGES;

    const float* c_w1[3] = { (const float*)d_in[3],  (const float*)d_in[7],  (const float*)d_in[11] };
    const float* c_b1[3] = { (const float*)d_in[4],  (const float*)d_in[8],  (const float*)d_in[12] };
    const float* c_w2[3] = { (const float*)d_in[5],  (const float*)d_in[9],  (const float*)d_in[13] };
    const float* c_b2[3] = { (const float*)d_in[6],  (const float*)d_in[10], (const float*)d_in[14] };
    const float* out_w1 = (const float*)d_in[15];
    const float* out_b1 = (const float*)d_in[16];
    const float* out_w2 = (const float*)d_in[17];
    const float* out_b2 = (const float*)d_in[18];

    // ---- Workspace layout (16B aligned) ----
    char* p = (char*)d_ws;
    auto alloc = [&](size_t bytes) {
        char* r = p;
        p += (bytes + 15) & ~(size_t)15;
        return r;
    };
    ushort* xbf  = (ushort*)alloc((size_t)N_NODES * IN_C * 2);   // planar [4][N][32]
    ushort* bufA = (ushort*)alloc((size_t)N_NODES * HID * 2);    // planar [8][N][32]
    ushort* bufB = (ushort*)alloc((size_t)N_NODES * HID * 2);    // row-major agg output
    ushort* wt[6];
    wt[0] = (ushort*)alloc((size_t)IN_C * HID * 2);
    for (int i = 1; i < 6; ++i) wt[i] = (ushort*)alloc((size_t)HID * HID * 2);
    float* sums   = (float*)alloc((size_t)N_GRAPHS * HID * 4);
    int* deg       = (int*)alloc((size_t)N_NODES * 4);
    int* rowptr    = (int*)alloc((size_t)(N_NODES + 1) * 4);
    int* blockSums = (int*)alloc(256 * 4);
    int* rank      = (int*)alloc((size_t)N_EDGES * 4);
    int* srcSorted = (int*)alloc((size_t)N_EDGES * 4);

    const int nb = (N_NODES + 255) / 256;

    // ---- Prep: one dispatch for casts + transposes + zeroing ----
    {
        PrepArgs a;
        a.x = x;
        a.w[0] = c_w1[0]; a.w[1] = c_w2[0];
        a.w[2] = c_w1[1]; a.w[3] = c_w2[1];
        a.w[4] = c_w1[2]; a.w[5] = c_w2[2];
        a.xbf = xbf;
        for (int i = 0; i < 6; ++i) a.wt[i] = wt[i];
        a.deg = deg;
        a.sums = sums;
        prep_kernel<<<2048, 256, 0, stream>>>(a);
    }

    // ---- Build CSR by dst: deg+rank -> scan -> sharded atomic-free scatter ----
    deg_rank_kernel<<<(N_EDGES + 255) / 256, 256, 0, stream>>>(dst, deg, rank);
    scan_block<<<nb, 256, 0, stream>>>(deg, rowptr, blockSums);
    add_offsets_fused<<<nb, 256, 0, stream>>>(rowptr, blockSums, rowptr, nb);
    {
        const int chunks = (N_EDGES + EDGES_PER_BLK - 1) / EDGES_PER_BLK;  // 391
        scatter_edges_sharded<<<chunks * NSHARD, 256, 0, stream>>>(src, dst, rank, rowptr, srcSorted);
    }

    const int nodeBlks = (N_NODES + 63) / 64;        // 782 (even, needed for PER=2)
    const int aggX128  = nodeBlks * (IN_C / 32);     // 3128
    const int aggX256  = nodeBlks * (HID / 32);      // 6256
    const int NPERS    = 256;                        // persistent MLP grid (1/CU)

    // ---- Layer 0 (C_in = 128) ----
    gin_aggregate_planar<IN_C><<<aggX128, 256, 0, stream>>>(xbf, rowptr, srcSorted, bufB);
    gin_mlp_persist<IN_C, false><<<NPERS, 512, 0, stream>>>(bufB, wt[0], c_b1[0], wt[1], c_b2[0],
                                                            bufA, batch, sums, N_NODES, nodeBlks, NPERS);

    // ---- Layer 1 (C = 256) ----
    gin_aggregate_planar<HID><<<aggX256, 256, 0, stream>>>(bufA, rowptr, srcSorted, bufB);
    gin_mlp_persist<HID, false><<<NPERS, 512, 0, stream>>>(bufB, wt[2], c_b1[1], wt[3], c_b2[1],
                                                           bufA, batch, sums, N_NODES, nodeBlks, NPERS);

    // ---- Layer 2 (C = 256) with fused global mean-pool accumulation ----
    gin_aggregate_planar<HID><<<aggX256, 256, 0, stream>>>(bufA, rowptr, srcSorted, bufB);
    gin_mlp_persist<HID, true><<<NPERS, 512, 0, stream>>>(bufB, wt[4], c_b1[2], wt[5], c_b2[2],
                                                          bufA, batch, sums, N_NODES, nodeBlks, NPERS);

    // ---- Head MLP ----
    final_mlp_kernel<<<N_GRAPHS, 256, 0, stream>>>(sums, batch, out_w1, out_b1,
                                                   out_w2, out_b2, (float*)d_out);
}

// Round 11
// 376.149 us; speedup vs baseline: 1.0619x; 1.0546x over previous
//
#include <hip/hip_runtime.h>

#define N_NODES 50000
#define N_EDGES 800000
#define N_GRAPHS 512
#define IN_C 128
#define HID 256
#define OUT_C 16

typedef __attribute__((ext_vector_type(8))) short short8;
typedef __attribute__((ext_vector_type(4))) float f32x4;

__device__ __forceinline__ float bf2f(unsigned short u) {
    return __uint_as_float(((unsigned int)u) << 16);
}
__device__ __forceinline__ unsigned short f2bf(float f) {
    unsigned int u = __float_as_uint(f);
    u += 0x7fff + ((u >> 16) & 1);   // RNE
    return (unsigned short)(u >> 16);
}

// Planar layout: features stored as [C/32 planes][N_NODES][32 cols] bf16.
// Each plane is 50000*64B = 3.2 MB (contiguous) -> fits one XCD's 4 MB L2.
#define PLANE_ELEMS ((long)N_NODES * 32)

// ===========================================================================
// Prep (single dispatch): x -> bf16 PLANAR, zero deg, zero sums.
// (Weight transposes moved to transpose_weights: the strided reads here were
// fully uncoalesced — ~50MB of line fetches for 1.4MB of payload.)
// ===========================================================================
struct PrepArgs {
    const float* x;
    ushort* xbf;            // planar [4][N][32]
    int* deg;
    float* sums;
};

__global__ __launch_bounds__(256) void prep_kernel(PrepArgs a) {
    const int X4    = N_NODES * IN_C / 4;
    const int D4    = N_NODES / 4;
    const int DBASE = X4;
    const int SBASE = DBASE + D4;
    const int S4    = N_GRAPHS * HID / 4;
    const long total = (long)SBASE + S4;

    long stride = (long)gridDim.x * blockDim.x;
    for (long i = (long)blockIdx.x * blockDim.x + threadIdx.x; i < total; i += stride) {
        if (i < X4) {
            float4 v = ((const float4*)a.x)[i];
            ushort4 o;
            o.x = f2bf(v.x); o.y = f2bf(v.y); o.z = f2bf(v.z); o.w = f2bf(v.w);
            long e = i * 4;
            int node = (int)(e >> 7);         // /128
            int col  = (int)(e & 127);
            long off = (long)(col >> 5) * PLANE_ELEMS + (long)node * 32 + (col & 31);
            *(ushort4*)(a.xbf + off) = o;
        } else if (i < SBASE) {
            ((int4*)a.deg)[i - DBASE] = make_int4(0, 0, 0, 0);
        } else {
            ((float4*)a.sums)[i - SBASE] = make_float4(0.f, 0.f, 0.f, 0.f);
        }
    }
}

// ===========================================================================
// Weight transpose via 32x32 LDS tiles: coalesced reads AND writes.
// w (K x 256 fp32, row-major) -> wt (256 x K bf16). 6 weights, 352 tiles.
// tile[32][33] ints: write phase reads tile[tk][n] with consecutive tk ->
// addr stride 33*4B -> all 32 banks hit once (conflict-free).
// ===========================================================================
struct TransArgs {
    const float* w[6];
    ushort* wt[6];
};

__global__ __launch_bounds__(256) void transpose_weights(TransArgs a) {
    __shared__ int tile[32][33];
    int bt = blockIdx.x;
    int wi, K, rel;
    if (bt < 32) { wi = 0; K = 128; rel = bt; }
    else { wi = 1 + (bt - 32) / 64; K = 256; rel = (bt - 32) % 64; }
    int k0 = (rel >> 3) * 32;
    int n0 = (rel & 7) * 32;

    const float* w = a.w[wi];
    ushort* wt = a.wt[wi];

    int t = threadIdx.x;
    int tn = t & 31, tk4 = t >> 5;       // read: coalesced over n
    #pragma unroll
    for (int r = 0; r < 4; ++r) {
        int row = tk4 + r * 8;           // k-offset within tile
        tile[row][tn] = f2bf(w[(long)(k0 + row) * HID + n0 + tn]);
    }
    __syncthreads();
    int tk2 = t & 31, tn4 = t >> 5;      // write: coalesced over k
    #pragma unroll
    for (int r = 0; r < 4; ++r) {
        int n2 = tn4 + r * 8;
        wt[(long)(n0 + n2) * K + k0 + tk2] = (ushort)tile[tk2][n2];
    }
}

// ===========================================================================
// CSR build: deg+rank in one atomic pass -> scan -> XCD-sharded atomic-free
// scatter. rank[e] = position of edge e within its dst segment.
// srcSorted is USHORT (N_NODES < 65536): halves the index-stream footprint
// so {plane 3.2MB + indices 1.6MB} better fits the 4MB per-XCD L2.
// ===========================================================================
__global__ void deg_rank_kernel(const int* __restrict__ dst, int* __restrict__ deg,
                                int* __restrict__ rank) {
    int e = blockIdx.x * blockDim.x + threadIdx.x;
    if (e < N_EDGES) rank[e] = atomicAdd(&deg[dst[e]], 1);
}

__global__ __launch_bounds__(256) void scan_block(const int* __restrict__ deg,
                                                  int* __restrict__ partial,
                                                  int* __restrict__ blockSums) {
    __shared__ int s[256];
    int t = threadIdx.x;
    int i = blockIdx.x * 256 + t;
    int v = (i < N_NODES) ? deg[i] : 0;
    s[t] = v;
    __syncthreads();
    #pragma unroll
    for (int off = 1; off < 256; off <<= 1) {
        int add = (t >= off) ? s[t - off] : 0;
        __syncthreads();
        s[t] += add;
        __syncthreads();
    }
    if (i < N_NODES) partial[i] = s[t] - v;
    if (t == 255) blockSums[blockIdx.x] = s[255];
}

__global__ __launch_bounds__(256) void add_offsets_fused(
    const int* __restrict__ partial, const int* __restrict__ blockSums,
    int* __restrict__ rowptr, int nb) {
    __shared__ int s[256];
    __shared__ int myOff;
    int t = threadIdx.x;
    int v = (t < nb) ? blockSums[t] : 0;
    s[t] = v;
    __syncthreads();
    #pragma unroll
    for (int off = 1; off < 256; off <<= 1) {
        int add = (t >= off) ? s[t - off] : 0;
        __syncthreads();
        s[t] += add;
        __syncthreads();
    }
    if (t == blockIdx.x) myOff = s[t] - v;
    __syncthreads();
    int i = blockIdx.x * 256 + t;
    if (i < N_NODES) rowptr[i] = partial[i] + myOff;
    if (i == 0) rowptr[N_NODES] = N_EDGES;
}

#define NSHARD 8
#define SHARD_SZ ((N_NODES + NSHARD - 1) / NSHARD)   // 6250
#define EDGES_PER_BLK 2048

__global__ __launch_bounds__(256) void scatter_edges_sharded(
    const int* __restrict__ src, const int* __restrict__ dst,
    const int* __restrict__ rank, const int* __restrict__ rowptr,
    ushort* __restrict__ srcSorted) {
    int b = blockIdx.x;
    int shard = b & 7;
    int chunk = b >> 3;
    int lo = shard * SHARD_SZ;
    int hi = lo + SHARD_SZ;
    int base = chunk * EDGES_PER_BLK + threadIdx.x;
    #pragma unroll
    for (int u = 0; u < EDGES_PER_BLK / 256; ++u) {
        int e = base + u * 256;
        if (e < N_EDGES) {
            int d = dst[e];
            if (d >= lo && d < hi)
                srcSorted[rowptr[d] + rank[e]] = (ushort)src[e];
        }
    }
}

// ===========================================================================
// Aggregation (R8 structure): planar-in / row-major-out. Cached index loads
// (ushort), nt output stores.
// ===========================================================================
template <int C>
__global__ __launch_bounds__(256) void gin_aggregate_planar(
    const ushort* __restrict__ hp,     // planar [C/32][N][32]
    const int* __restrict__ rowptr,
    const ushort* __restrict__ srcIdx,
    ushort* __restrict__ out)          // row-major [N][C]
{
    constexpr int NC  = C / 32;        // 4 (C=128) or 8 (C=256)
    constexpr int PER = 8 / NC;        // XCDs per plane (2 or 1)

    int b  = blockIdx.x;
    int x8 = b & 7;                    // presumed XCD id (round-robin)
    int chunk   = x8 / PER;
    int nodeblk = (b >> 3) * PER + (x8 & (PER - 1));

    int lane = threadIdx.x & 63;
    int wave = threadIdx.x >> 6;
    int grp  = lane >> 2;              // 0..15: node within wave
    int l    = lane & 3;               // 4 lanes x 8 bf16 = 32 cols
    int node = nodeblk * 64 + wave * 16 + grp;
    if (node >= N_NODES) return;

    const ushort* plane = hp + (long)chunk * PLANE_ELEMS + l * 8;

    float acc[8];
    {
        short8 sv = *(const short8*)(plane + (long)node * 32);
        #pragma unroll
        for (int v = 0; v < 8; ++v) acc[v] = bf2f((unsigned short)sv[v]);
    }

    int beg = rowptr[node], end = rowptr[node + 1];
    int k = beg;
    for (; k + 8 <= end; k += 8) {
        int si[8];
        #pragma unroll
        for (int u = 0; u < 8; ++u) si[u] = srcIdx[k + u];
        short8 r[8];
        #pragma unroll
        for (int u = 0; u < 8; ++u) r[u] = *(const short8*)(plane + (long)si[u] * 32);
        #pragma unroll
        for (int u = 0; u < 8; ++u)
            #pragma unroll
            for (int v = 0; v < 8; ++v) acc[v] += bf2f((unsigned short)r[u][v]);
    }
    for (; k + 2 <= end; k += 2) {
        int si0 = srcIdx[k], si1 = srcIdx[k + 1];
        short8 r0 = *(const short8*)(plane + (long)si0 * 32);
        short8 r1 = *(const short8*)(plane + (long)si1 * 32);
        #pragma unroll
        for (int v = 0; v < 8; ++v) acc[v] += bf2f((unsigned short)r0[v]);
        #pragma unroll
        for (int v = 0; v < 8; ++v) acc[v] += bf2f((unsigned short)r1[v]);
    }
    if (k < end) {
        short8 r = *(const short8*)(plane + (long)srcIdx[k] * 32);
        #pragma unroll
        for (int v = 0; v < 8; ++v) acc[v] += bf2f((unsigned short)r[v]);
    }

    short8 o;
    #pragma unroll
    for (int v = 0; v < 8; ++v) o[v] = (short)f2bf(acc[v]);
    __builtin_nontemporal_store(o, (short8*)(out + (long)node * C + chunk * 32 + l * 8));
}

// ===========================================================================
// PERSISTENT fused 2-layer MLP (R10 form, unchanged).
// ===========================================================================
template <int K1, bool FUSE_POOL>
__global__ __launch_bounds__(512, 2) void gin_mlp_persist(
    const ushort* __restrict__ A,
    const ushort* __restrict__ w1t,
    const float* __restrict__ b1,
    const ushort* __restrict__ w2t,
    const float* __restrict__ b2,
    ushort* __restrict__ out,          // planar [8][N][32]
    const int* __restrict__ batch,
    float* __restrict__ sums,
    int M, int nTiles, int nPers)
{
    constexpr int NCH1 = K1 / 8;        // 16 or 32
    constexpr int NSLOT1 = 64 * NCH1;   // 1024 or 2048
    constexpr int NS1 = K1 / 32;        // 4 or 8
    constexpr int PFN = NSLOT1 / 512;   // 2 or 4 short8 per thread per stage

    __shared__ short LsA[NSLOT1 * 8];   // 16 KB (K=128) / 32 KB (K=256)
    __shared__ short LsH[2048 * 8];     // 32 KB

    int t = threadIdx.x;
    int lane = t & 63;
    int wv = t >> 6;                    // 0..7
    int quad = lane >> 4;
    int l15 = lane & 15;
    int swz = l15 & 7;
    int col0 = wv * 32;

    // ---- Preload W1 + W2 slices and biases into registers (once), pinned ----
    short8 w1r[NS1 * 2];
    #pragma unroll
    for (int s = 0; s < NS1; ++s)
        #pragma unroll
        for (int j = 0; j < 2; ++j)
            w1r[s * 2 + j] = *(const short8*)(w1t + (long)(col0 + j * 16 + l15) * K1 + s * 32 + quad * 8);
    short8 w2r[16];
    #pragma unroll
    for (int s = 0; s < 8; ++s)
        #pragma unroll
        for (int j = 0; j < 2; ++j)
            w2r[s * 2 + j] = *(const short8*)(w2t + (long)(col0 + j * 16 + l15) * 256 + s * 32 + quad * 8);
    #pragma unroll
    for (int i = 0; i < NS1 * 2; ++i) asm volatile("" : "+v"(w1r[i]));
    #pragma unroll
    for (int i = 0; i < 16; ++i) asm volatile("" : "+v"(w2r[i]));

    float bv1[2], bv2[2];
    #pragma unroll
    for (int j = 0; j < 2; ++j) {
        bv1[j] = b1[col0 + j * 16 + l15];
        bv2[j] = b2[col0 + j * 16 + l15];
    }

    // ---- Per-thread staging geometry (tile-invariant) ----
    int prow[PFN], pkcB[PFN];
    #pragma unroll
    for (int c = 0; c < PFN; ++c) {
        int s = c * 512 + t;
        prow[c] = s / NCH1;
        int kcs = s & (NCH1 - 1);
        pkcB[c] = (kcs ^ (prow[c] & 7)) * 8;
    }

    // ---- Contiguous tile range for this block ----
    int t0 = (int)(((long)blockIdx.x * nTiles) / nPers);
    int t1 = (int)(((long)(blockIdx.x + 1) * nTiles) / nPers);
    if (t0 >= t1) return;

    const f32x4 zero = {0.f, 0.f, 0.f, 0.f};

    short8 pf[PFN];
    {
        int row0 = t0 * 64;
        #pragma unroll
        for (int c = 0; c < PFN; ++c) {
            int grow = row0 + prow[c];
            if (grow >= M) grow = M - 1;
            pf[c] = *(const short8*)(A + (long)grow * K1 + pkcB[c]);
        }
    }

    for (int ti = t0; ti < t1; ++ti) {
        int row0 = ti * 64;

        #pragma unroll
        for (int c = 0; c < PFN; ++c)
            *(short8*)&LsA[(c * 512 + t) * 8] = pf[c];
        if (ti + 1 < t1) {
            int nrow0 = (ti + 1) * 64;
            #pragma unroll
            for (int c = 0; c < PFN; ++c) {
                int grow = nrow0 + prow[c];
                if (grow >= M) grow = M - 1;
                pf[c] = *(const short8*)(A + (long)grow * K1 + pkcB[c]);
            }
        }
        __syncthreads();                       // B1

        f32x4 acc[4][2];
        #pragma unroll
        for (int i = 0; i < 4; ++i)
            #pragma unroll
            for (int j = 0; j < 2; ++j) acc[i][j] = zero;

        #pragma unroll
        for (int s = 0; s < NS1; ++s) {
            #pragma unroll
            for (int i = 0; i < 4; ++i) {
                int row = i * 16 + l15;
                int slot = row * NCH1 + ((s * 4 + quad) ^ swz);
                short8 a = *(const short8*)&LsA[slot * 8];
                acc[i][0] = __builtin_amdgcn_mfma_f32_16x16x32_bf16(a, w1r[s * 2 + 0], acc[i][0], 0, 0, 0);
                acc[i][1] = __builtin_amdgcn_mfma_f32_16x16x32_bf16(a, w1r[s * 2 + 1], acc[i][1], 0, 0, 0);
            }
        }
        __syncthreads();                       // B2

        #pragma unroll
        for (int i = 0; i < 4; ++i)
            #pragma unroll
            for (int j = 0; j < 2; ++j) {
                int col = col0 + j * 16 + l15;
                int kc2 = col >> 3, sub = col & 7;
                #pragma unroll
                for (int r = 0; r < 4; ++r) {
                    int row = i * 16 + quad * 4 + r;
                    int slot = row * 32 + (kc2 ^ (row & 7));
                    float o = fmaxf(acc[i][j][r] + bv1[j], 0.f);
                    LsH[slot * 8 + sub] = (short)f2bf(o);
                }
            }
        __syncthreads();                       // B3

        #pragma unroll
        for (int i = 0; i < 4; ++i)
            #pragma unroll
            for (int j = 0; j < 2; ++j) acc[i][j] = zero;

        #pragma unroll
        for (int s = 0; s < 8; ++s) {
            #pragma unroll
            for (int i = 0; i < 4; ++i) {
                int row = i * 16 + l15;
                int slot = row * 32 + ((s * 4 + quad) ^ swz);
                short8 a = *(const short8*)&LsH[slot * 8];
                acc[i][0] = __builtin_amdgcn_mfma_f32_16x16x32_bf16(a, w2r[s * 2 + 0], acc[i][0], 0, 0, 0);
                acc[i][1] = __builtin_amdgcn_mfma_f32_16x16x32_bf16(a, w2r[s * 2 + 1], acc[i][1], 0, 0, 0);
            }
        }

        if constexpr (!FUSE_POOL) {
            #pragma unroll
            for (int i = 0; i < 4; ++i)
                #pragma unroll
                for (int r = 0; r < 4; ++r) {
                    int grow = row0 + i * 16 + quad * 4 + r;
                    if (grow >= M) continue;
                    #pragma unroll
                    for (int j = 0; j < 2; ++j) {
                        int col = col0 + j * 16 + l15;
                        float o = fmaxf(acc[i][j][r] + bv2[j], 0.f);
                        out[(long)(col >> 5) * PLANE_ELEMS + (long)grow * 32 + (col & 31)] = f2bf(o);
                    }
                }
        } else {
            float pacc[2];
            #pragma unroll
            for (int j = 0; j < 2; ++j) pacc[j] = 0.f;
            int cur = -1;
            #pragma unroll
            for (int i = 0; i < 4; ++i) {
                #pragma unroll
                for (int r = 0; r < 4; ++r) {
                    int row = row0 + i * 16 + quad * 4 + r;
                    if (row >= M) continue;
                    int g = batch[row];
                    if (g != cur) {
                        if (cur >= 0) {
                            #pragma unroll
                            for (int j = 0; j < 2; ++j)
                                atomicAdd(&sums[(long)cur * 256 + col0 + j * 16 + l15], pacc[j]);
                        }
                        cur = g;
                        #pragma unroll
                        for (int j = 0; j < 2; ++j) pacc[j] = 0.f;
                    }
                    #pragma unroll
                    for (int j = 0; j < 2; ++j)
                        pacc[j] += fmaxf(acc[i][j][r] + bv2[j], 0.f);
                }
            }
            if (cur >= 0) {
                #pragma unroll
                for (int j = 0; j < 2; ++j)
                    atomicAdd(&sums[(long)cur * 256 + col0 + j * 16 + l15], pacc[j]);
            }
        }
    }
}

// ===========================================================================
// Head MLP (fp32): one block per graph; count via binary search on batch.
// ===========================================================================
__global__ __launch_bounds__(256) void final_mlp_kernel(
    const float* __restrict__ sums, const int* __restrict__ batch,
    const float* __restrict__ w1, const float* __restrict__ b1,
    const float* __restrict__ w2, const float* __restrict__ b2,
    float* __restrict__ out) {
    __shared__ float row[HID];
    __shared__ float hid[HID];
    __shared__ int cntS;
    int g = blockIdx.x;
    int t = threadIdx.x;
    if (t == 0) {
        int lo = 0, hi = N_NODES;
        while (lo < hi) { int m = (lo + hi) >> 1; if (batch[m] < g) lo = m + 1; else hi = m; }
        int lo2 = lo, hi2 = N_NODES;
        while (lo2 < hi2) { int m = (lo2 + hi2) >> 1; if (batch[m] < g + 1) lo2 = m + 1; else hi2 = m; }
        cntS = lo2 - lo;
    }
    __syncthreads();
    float cnt = fmaxf((float)cntS, 1.0f);
    row[t] = sums[(long)g * HID + t] / cnt;
    __syncthreads();
    float acc = b1[t];
    for (int k = 0; k < HID; ++k) acc += row[k] * w1[k * HID + t];
    hid[t] = fmaxf(acc, 0.f);
    __syncthreads();
    if (t < OUT_C) {
        float o = b2[t];
        for (int k = 0; k < HID; ++k) o += hid[k] * w2[k * OUT_C + t];
        out[(long)g * OUT_C + t] = o;
    }
}

// ---------------------------------------------------------------------------
extern "C" void kernel_launch(void* const* d_in, const int* in_sizes, int n_in,
                              void* d_out, int out_size, void* d_ws, size_t ws_size,
                              hipStream_t stream) {
    const float* x     = (const float*)d_in[0];
    const int*   ei    = (const int*)d_in[1];
    const int*   batch = (const int*)d_in[2];
    const int*   src   = ei;
    const int*   dst   = ei + N_EDGES;

    const float* c_w1[3] = { (const float*)d_in[3],  (const float*)d_in[7],  (const float*)d_in[11] };
    const float* c_b1[3] = { (const float*)d_in[4],  (const float*)d_in[8],  (const float*)d_in[12] };
    const float* c_w2[3] = { (const float*)d_in[5],  (const float*)d_in[9],  (const float*)d_in[13] };
    const float* c_b2[3] = { (const float*)d_in[6],  (const float*)d_in[10], (const float*)d_in[14] };
    const float* out_w1 = (const float*)d_in[15];
    const float* out_b1 = (const float*)d_in[16];
    const float* out_w2 = (const float*)d_in[17];
    const float* out_b2 = (const float*)d_in[18];

    // ---- Workspace layout (16B aligned) ----
    char* p = (char*)d_ws;
    auto alloc = [&](size_t bytes) {
        char* r = p;
        p += (bytes + 15) & ~(size_t)15;
        return r;
    };
    ushort* xbf  = (ushort*)alloc((size_t)N_NODES * IN_C * 2);   // planar [4][N][32]
    ushort* bufA = (ushort*)alloc((size_t)N_NODES * HID * 2);    // planar [8][N][32]
    ushort* bufB = (ushort*)alloc((size_t)N_NODES * HID * 2);    // row-major agg output
    ushort* wt[6];
    wt[0] = (ushort*)alloc((size_t)IN_C * HID * 2);
    for (int i = 1; i < 6; ++i) wt[i] = (ushort*)alloc((size_t)HID * HID * 2);
    float* sums   = (float*)alloc((size_t)N_GRAPHS * HID * 4);
    int* deg       = (int*)alloc((size_t)N_NODES * 4);
    int* rowptr    = (int*)alloc((size_t)(N_NODES + 1) * 4);
    int* blockSums = (int*)alloc(256 * 4);
    int* rank      = (int*)alloc((size_t)N_EDGES * 4);
    ushort* srcSorted = (ushort*)alloc((size_t)N_EDGES * 2);     // USHORT indices

    const int nb = (N_NODES + 255) / 256;

    // ---- Prep: casts + zeroing ----
    {
        PrepArgs a;
        a.x = x;
        a.xbf = xbf;
        a.deg = deg;
        a.sums = sums;
        prep_kernel<<<2048, 256, 0, stream>>>(a);
    }
    // ---- Coalesced weight transposes (352 tiles of 32x32) ----
    {
        TransArgs ta;
        ta.w[0] = c_w1[0]; ta.w[1] = c_w2[0];
        ta.w[2] = c_w1[1]; ta.w[3] = c_w2[1];
        ta.w[4] = c_w1[2]; ta.w[5] = c_w2[2];
        for (int i = 0; i < 6; ++i) ta.wt[i] = wt[i];
        transpose_weights<<<352, 256, 0, stream>>>(ta);
    }

    // ---- Build CSR by dst: deg+rank -> scan -> sharded atomic-free scatter ----
    deg_rank_kernel<<<(N_EDGES + 255) / 256, 256, 0, stream>>>(dst, deg, rank);
    scan_block<<<nb, 256, 0, stream>>>(deg, rowptr, blockSums);
    add_offsets_fused<<<nb, 256, 0, stream>>>(rowptr, blockSums, rowptr, nb);
    {
        const int chunks = (N_EDGES + EDGES_PER_BLK - 1) / EDGES_PER_BLK;  // 391
        scatter_edges_sharded<<<chunks * NSHARD, 256, 0, stream>>>(src, dst, rank, rowptr, srcSorted);
    }

    const int nodeBlks = (N_NODES + 63) / 64;        // 782 (even, needed for PER=2)
    const int aggX128  = nodeBlks * (IN_C / 32);     // 3128
    const int aggX256  = nodeBlks * (HID / 32);      // 6256
    const int NPERS    = 256;                        // persistent MLP grid (1/CU)

    // ---- Layer 0 (C_in = 128) ----
    gin_aggregate_planar<IN_C><<<aggX128, 256, 0, stream>>>(xbf, rowptr, srcSorted, bufB);
    gin_mlp_persist<IN_C, false><<<NPERS, 512, 0, stream>>>(bufB, wt[0], c_b1[0], wt[1], c_b2[0],
                                                            bufA, batch, sums, N_NODES, nodeBlks, NPERS);

    // ---- Layer 1 (C = 256) ----
    gin_aggregate_planar<HID><<<aggX256, 256, 0, stream>>>(bufA, rowptr, srcSorted, bufB);
    gin_mlp_persist<HID, false><<<NPERS, 512, 0, stream>>>(bufB, wt[2], c_b1[1], wt[3], c_b2[1],
                                                           bufA, batch, sums, N_NODES, nodeBlks, NPERS);

    // ---- Layer 2 (C = 256) with fused global mean-pool accumulation ----
    gin_aggregate_planar<HID><<<aggX256, 256, 0, stream>>>(bufA, rowptr, srcSorted, bufB);
    gin_mlp_persist<HID, true><<<NPERS, 512, 0, stream>>>(bufB, wt[4], c_b1[2], wt[5], c_b2[2],
                                                          bufA, batch, sums, N_NODES, nodeBlks, NPERS);

    // ---- Head MLP ----
    final_mlp_kernel<<<N_GRAPHS, 256, 0, stream>>>(sums, batch, out_w1, out_b1,
                                                   out_w2, out_b2, (float*)d_out);
}

// Round 13
// 373.651 us; speedup vs baseline: 1.0690x; 1.0067x over previous
//
#include <hip/hip_runtime.h>

#define N_NODES 50000
#define N_EDGES 800000
#define N_GRAPHS 512
#define IN_C 128
#define HID 256
#define OUT_C 16

typedef __attribute__((ext_vector_type(8))) short short8;
typedef __attribute__((ext_vector_type(4))) float f32x4;

__device__ __forceinline__ float bf2f(unsigned short u) {
    return __uint_as_float(((unsigned int)u) << 16);
}
__device__ __forceinline__ unsigned short f2bf(float f) {
    unsigned int u = __float_as_uint(f);
    u += 0x7fff + ((u >> 16) & 1);   // RNE
    return (unsigned short)(u >> 16);
}

// Planar layout: features stored as [C/32 planes][N_NODES][32 cols] bf16.
// Each plane is 50000*64B = 3.2 MB (contiguous) -> fits one XCD's 4 MB L2.
#define PLANE_ELEMS ((long)N_NODES * 32)

// ===========================================================================
// Prep (single dispatch): x -> bf16 PLANAR, zero deg, zero sums.
// ===========================================================================
struct PrepArgs {
    const float* x;
    ushort* xbf;            // planar [4][N][32]
    int* deg;
    float* sums;
};

__global__ __launch_bounds__(256) void prep_kernel(PrepArgs a) {
    const int X4    = N_NODES * IN_C / 4;
    const int D4    = N_NODES / 4;
    const int DBASE = X4;
    const int SBASE = DBASE + D4;
    const int S4    = N_GRAPHS * HID / 4;
    const long total = (long)SBASE + S4;

    long stride = (long)gridDim.x * blockDim.x;
    for (long i = (long)blockIdx.x * blockDim.x + threadIdx.x; i < total; i += stride) {
        if (i < X4) {
            float4 v = ((const float4*)a.x)[i];
            ushort4 o;
            o.x = f2bf(v.x); o.y = f2bf(v.y); o.z = f2bf(v.z); o.w = f2bf(v.w);
            long e = i * 4;
            int node = (int)(e >> 7);         // /128
            int col  = (int)(e & 127);
            long off = (long)(col >> 5) * PLANE_ELEMS + (long)node * 32 + (col & 31);
            *(ushort4*)(a.xbf + off) = o;
        } else if (i < SBASE) {
            ((int4*)a.deg)[i - DBASE] = make_int4(0, 0, 0, 0);
        } else {
            ((float4*)a.sums)[i - SBASE] = make_float4(0.f, 0.f, 0.f, 0.f);
        }
    }
}

// ===========================================================================
// Weight transpose via 32x32 LDS tiles: coalesced reads AND writes.
// ===========================================================================
struct TransArgs {
    const float* w[6];
    ushort* wt[6];
};

__global__ __launch_bounds__(256) void transpose_weights(TransArgs a) {
    __shared__ int tile[32][33];
    int bt = blockIdx.x;
    int wi, K, rel;
    if (bt < 32) { wi = 0; K = 128; rel = bt; }
    else { wi = 1 + (bt - 32) / 64; K = 256; rel = (bt - 32) % 64; }
    int k0 = (rel >> 3) * 32;
    int n0 = (rel & 7) * 32;

    const float* w = a.w[wi];
    ushort* wt = a.wt[wi];

    int t = threadIdx.x;
    int tn = t & 31, tk4 = t >> 5;       // read: coalesced over n
    #pragma unroll
    for (int r = 0; r < 4; ++r) {
        int row = tk4 + r * 8;           // k-offset within tile
        tile[row][tn] = f2bf(w[(long)(k0 + row) * HID + n0 + tn]);
    }
    __syncthreads();
    int tk2 = t & 31, tn4 = t >> 5;      // write: coalesced over k
    #pragma unroll
    for (int r = 0; r < 4; ++r) {
        int n2 = tn4 + r * 8;
        wt[(long)(n0 + n2) * K + k0 + tk2] = (ushort)tile[tk2][n2];
    }
}

// ===========================================================================
// CSR build: deg+rank+pack in one atomic pass -> scan -> XCD-sharded
// atomic-free scatter. pack = (dst<<16)|src (both < 65536): scatter reads
// ONE 4B word + 2B rank per edge instead of 12B -> per-shard re-stream
// traffic halved. rank is ushort (max degree ~50 for this input).
// ===========================================================================
__global__ void deg_rank_kernel(const int* __restrict__ src, const int* __restrict__ dst,
                                int* __restrict__ deg, ushort* __restrict__ rank16,
                                uint* __restrict__ pack) {
    int e = blockIdx.x * blockDim.x + threadIdx.x;
    if (e < N_EDGES) {
        int d = dst[e];
        rank16[e] = (ushort)atomicAdd(&deg[d], 1);
        pack[e] = ((uint)d << 16) | (uint)src[e];
    }
}

__global__ __launch_bounds__(256) void scan_block(const int* __restrict__ deg,
                                                  int* __restrict__ partial,
                                                  int* __restrict__ blockSums) {
    __shared__ int s[256];
    int t = threadIdx.x;
    int i = blockIdx.x * 256 + t;
    int v = (i < N_NODES) ? deg[i] : 0;
    s[t] = v;
    __syncthreads();
    #pragma unroll
    for (int off = 1; off < 256; off <<= 1) {
        int add = (t >= off) ? s[t - off] : 0;
        __syncthreads();
        s[t] += add;
        __syncthreads();
    }
    if (i < N_NODES) partial[i] = s[t] - v;
    if (t == 255) blockSums[blockIdx.x] = s[255];
}

__global__ __launch_bounds__(256) void add_offsets_fused(
    const int* __restrict__ partial, const int* __restrict__ blockSums,
    int* __restrict__ rowptr, int nb) {
    __shared__ int s[256];
    __shared__ int myOff;
    int t = threadIdx.x;
    int v = (t < nb) ? blockSums[t] : 0;
    s[t] = v;
    __syncthreads();
    #pragma unroll
    for (int off = 1; off < 256; off <<= 1) {
        int add = (t >= off) ? s[t - off] : 0;
        __syncthreads();
        s[t] += add;
        __syncthreads();
    }
    if (t == blockIdx.x) myOff = s[t] - v;
    __syncthreads();
    int i = blockIdx.x * 256 + t;
    if (i < N_NODES) rowptr[i] = partial[i] + myOff;
    if (i == 0) rowptr[N_NODES] = N_EDGES;
}

#define NSHARD 8
#define SHARD_SZ ((N_NODES + NSHARD - 1) / NSHARD)   // 6250
#define EDGES_PER_BLK 2048

__global__ __launch_bounds__(256) void scatter_edges_sharded(
    const uint* __restrict__ pack, const ushort* __restrict__ rank16,
    const int* __restrict__ rowptr, ushort* __restrict__ srcSorted) {
    int b = blockIdx.x;
    int shard = b & 7;
    int chunk = b >> 3;
    int lo = shard * SHARD_SZ;
    int hi = lo + SHARD_SZ;
    int base = chunk * EDGES_PER_BLK + threadIdx.x;
    #pragma unroll
    for (int u = 0; u < EDGES_PER_BLK / 256; ++u) {
        int e = base + u * 256;
        if (e < N_EDGES) {
            uint pk = pack[e];
            int d = (int)(pk >> 16);
            if (d >= lo && d < hi)
                srcSorted[rowptr[d] + rank16[e]] = (ushort)(pk & 0xFFFFu);
        }
    }
}

// ===========================================================================
// Aggregation: planar-in / row-major-out, with LDS-staged edge indices.
// The block's 64 nodes have a CONTIGUOUS srcSorted range (CSR) — stage it
// into LDS with one coalesced read, then gather indices from LDS. The
// per-XCD L2 then holds ONLY the 3.2MB plane during the gather (R11's
// ushort shrink confirmed L2 capacity is the lever). 16KB LDS, capacity
// 8192 edges (avg 1024, sigma 32 — global fallback never taken in practice).
// ===========================================================================
template <int C>
__global__ __launch_bounds__(256) void gin_aggregate_planar(
    const ushort* __restrict__ hp,     // planar [C/32][N][32]
    const int* __restrict__ rowptr,
    const ushort* __restrict__ srcIdx,
    ushort* __restrict__ out)          // row-major [N][C]
{
    constexpr int NC  = C / 32;        // 4 (C=128) or 8 (C=256)
    constexpr int PER = 8 / NC;        // XCDs per plane (2 or 1)

    __shared__ ushort sIdx[8192];

    int b  = blockIdx.x;
    int x8 = b & 7;                    // presumed XCD id (round-robin)
    int chunk   = x8 / PER;
    int nodeblk = (b >> 3) * PER + (x8 & (PER - 1));

    int n0 = nodeblk * 64;
    int nEnd = n0 + 64; if (nEnd > N_NODES) nEnd = N_NODES;
    int rbeg = rowptr[n0];
    int rend = rowptr[nEnd];
    int cnt  = rend - rbeg;
    bool useLds = (cnt <= 8192);
    if (useLds) {
        for (int i = threadIdx.x; i < cnt; i += 256)
            sIdx[i] = srcIdx[rbeg + i];
    }
    __syncthreads();

    int lane = threadIdx.x & 63;
    int wave = threadIdx.x >> 6;
    int grp  = lane >> 2;              // 0..15: node within wave
    int l    = lane & 3;               // 4 lanes x 8 bf16 = 32 cols
    int node = n0 + wave * 16 + grp;
    if (node >= N_NODES) return;

    const ushort* plane = hp + (long)chunk * PLANE_ELEMS + l * 8;

    float acc[8];
    {
        short8 sv = *(const short8*)(plane + (long)node * 32);
        #pragma unroll
        for (int v = 0; v < 8; ++v) acc[v] = bf2f((unsigned short)sv[v]);
    }

    int beg = rowptr[node], end = rowptr[node + 1];

    auto gather = [&](auto idxAt) {
        int k = beg;
        for (; k + 8 <= end; k += 8) {
            int si[8];
            #pragma unroll
            for (int u = 0; u < 8; ++u) si[u] = idxAt(k + u);
            short8 r[8];
            #pragma unroll
            for (int u = 0; u < 8; ++u) r[u] = *(const short8*)(plane + (long)si[u] * 32);
            #pragma unroll
            for (int u = 0; u < 8; ++u)
                #pragma unroll
                for (int v = 0; v < 8; ++v) acc[v] += bf2f((unsigned short)r[u][v]);
        }
        for (; k + 2 <= end; k += 2) {
            int si0 = idxAt(k), si1 = idxAt(k + 1);
            short8 r0 = *(const short8*)(plane + (long)si0 * 32);
            short8 r1 = *(const short8*)(plane + (long)si1 * 32);
            #pragma unroll
            for (int v = 0; v < 8; ++v) acc[v] += bf2f((unsigned short)r0[v]);
            #pragma unroll
            for (int v = 0; v < 8; ++v) acc[v] += bf2f((unsigned short)r1[v]);
        }
        if (k < end) {
            short8 r = *(const short8*)(plane + (long)idxAt(k) * 32);
            #pragma unroll
            for (int v = 0; v < 8; ++v) acc[v] += bf2f((unsigned short)r[v]);
        }
    };

    if (useLds) gather([&](int k) { return (int)sIdx[k - rbeg]; });
    else        gather([&](int k) { return (int)srcIdx[k]; });

    short8 o;
    #pragma unroll
    for (int v = 0; v < 8; ++v) o[v] = (short)f2bf(acc[v]);
    __builtin_nontemporal_store(o, (short8*)(out + (long)node * C + chunk * 32 + l * 8));
}

// ===========================================================================
// PERSISTENT fused 2-layer MLP (R10/R11 form — FROZEN: four structural
// variants all measure 45-52us; declared plateaued for this session).
// ===========================================================================
template <int K1, bool FUSE_POOL>
__global__ __launch_bounds__(512, 2) void gin_mlp_persist(
    const ushort* __restrict__ A,
    const ushort* __restrict__ w1t,
    const float* __restrict__ b1,
    const ushort* __restrict__ w2t,
    const float* __restrict__ b2,
    ushort* __restrict__ out,          // planar [8][N][32]
    const int* __restrict__ batch,
    float* __restrict__ sums,
    int M, int nTiles, int nPers)
{
    constexpr int NCH1 = K1 / 8;        // 16 or 32
    constexpr int NSLOT1 = 64 * NCH1;   // 1024 or 2048
    constexpr int NS1 = K1 / 32;        // 4 or 8
    constexpr int PFN = NSLOT1 / 512;   // 2 or 4 short8 per thread per stage

    __shared__ short LsA[NSLOT1 * 8];   // 16 KB (K=128) / 32 KB (K=256)
    __shared__ short LsH[2048 * 8];     // 32 KB

    int t = threadIdx.x;
    int lane = t & 63;
    int wv = t >> 6;                    // 0..7
    int quad = lane >> 4;
    int l15 = lane & 15;
    int swz = l15 & 7;
    int col0 = wv * 32;

    short8 w1r[NS1 * 2];
    #pragma unroll
    for (int s = 0; s < NS1; ++s)
        #pragma unroll
        for (int j = 0; j < 2; ++j)
            w1r[s * 2 + j] = *(const short8*)(w1t + (long)(col0 + j * 16 + l15) * K1 + s * 32 + quad * 8);
    short8 w2r[16];
    #pragma unroll
    for (int s = 0; s < 8; ++s)
        #pragma unroll
        for (int j = 0; j < 2; ++j)
            w2r[s * 2 + j] = *(const short8*)(w2t + (long)(col0 + j * 16 + l15) * 256 + s * 32 + quad * 8);
    #pragma unroll
    for (int i = 0; i < NS1 * 2; ++i) asm volatile("" : "+v"(w1r[i]));
    #pragma unroll
    for (int i = 0; i < 16; ++i) asm volatile("" : "+v"(w2r[i]));

    float bv1[2], bv2[2];
    #pragma unroll
    for (int j = 0; j < 2; ++j) {
        bv1[j] = b1[col0 + j * 16 + l15];
        bv2[j] = b2[col0 + j * 16 + l15];
    }

    int prow[PFN], pkcB[PFN];
    #pragma unroll
    for (int c = 0; c < PFN; ++c) {
        int s = c * 512 + t;
        prow[c] = s / NCH1;
        int kcs = s & (NCH1 - 1);
        pkcB[c] = (kcs ^ (prow[c] & 7)) * 8;
    }

    int t0 = (int)(((long)blockIdx.x * nTiles) / nPers);
    int t1 = (int)(((long)(blockIdx.x + 1) * nTiles) / nPers);
    if (t0 >= t1) return;

    const f32x4 zero = {0.f, 0.f, 0.f, 0.f};

    short8 pf[PFN];
    {
        int row0 = t0 * 64;
        #pragma unroll
        for (int c = 0; c < PFN; ++c) {
            int grow = row0 + prow[c];
            if (grow >= M) grow = M - 1;
            pf[c] = *(const short8*)(A + (long)grow * K1 + pkcB[c]);
        }
    }

    for (int ti = t0; ti < t1; ++ti) {
        int row0 = ti * 64;

        #pragma unroll
        for (int c = 0; c < PFN; ++c)
            *(short8*)&LsA[(c * 512 + t) * 8] = pf[c];
        if (ti + 1 < t1) {
            int nrow0 = (ti + 1) * 64;
            #pragma unroll
            for (int c = 0; c < PFN; ++c) {
                int grow = nrow0 + prow[c];
                if (grow >= M) grow = M - 1;
                pf[c] = *(const short8*)(A + (long)grow * K1 + pkcB[c]);
            }
        }
        __syncthreads();                       // B1

        f32x4 acc[4][2];
        #pragma unroll
        for (int i = 0; i < 4; ++i)
            #pragma unroll
            for (int j = 0; j < 2; ++j) acc[i][j] = zero;

        #pragma unroll
        for (int s = 0; s < NS1; ++s) {
            #pragma unroll
            for (int i = 0; i < 4; ++i) {
                int row = i * 16 + l15;
                int slot = row * NCH1 + ((s * 4 + quad) ^ swz);
                short8 a = *(const short8*)&LsA[slot * 8];
                acc[i][0] = __builtin_amdgcn_mfma_f32_16x16x32_bf16(a, w1r[s * 2 + 0], acc[i][0], 0, 0, 0);
                acc[i][1] = __builtin_amdgcn_mfma_f32_16x16x32_bf16(a, w1r[s * 2 + 1], acc[i][1], 0, 0, 0);
            }
        }
        __syncthreads();                       // B2

        #pragma unroll
        for (int i = 0; i < 4; ++i)
            #pragma unroll
            for (int j = 0; j < 2; ++j) {
                int col = col0 + j * 16 + l15;
                int kc2 = col >> 3, sub = col & 7;
                #pragma unroll
                for (int r = 0; r < 4; ++r) {
                    int row = i * 16 + quad * 4 + r;
                    int slot = row * 32 + (kc2 ^ (row & 7));
                    float o = fmaxf(acc[i][j][r] + bv1[j], 0.f);
                    LsH[slot * 8 + sub] = (short)f2bf(o);
                }
            }
        __syncthreads();                       // B3

        #pragma unroll
        for (int i = 0; i < 4; ++i)
            #pragma unroll
            for (int j = 0; j < 2; ++j) acc[i][j] = zero;

        #pragma unroll
        for (int s = 0; s < 8; ++s) {
            #pragma unroll
            for (int i = 0; i < 4; ++i) {
                int row = i * 16 + l15;
                int slot = row * 32 + ((s * 4 + quad) ^ swz);
                short8 a = *(const short8*)&LsH[slot * 8];
                acc[i][0] = __builtin_amdgcn_mfma_f32_16x16x32_bf16(a, w2r[s * 2 + 0], acc[i][0], 0, 0, 0);
                acc[i][1] = __builtin_amdgcn_mfma_f32_16x16x32_bf16(a, w2r[s * 2 + 1], acc[i][1], 0, 0, 0);
            }
        }

        if constexpr (!FUSE_POOL) {
            #pragma unroll
            for (int i = 0; i < 4; ++i)
                #pragma unroll
                for (int r = 0; r < 4; ++r) {
                    int grow = row0 + i * 16 + quad * 4 + r;
                    if (grow >= M) continue;
                    #pragma unroll
                    for (int j = 0; j < 2; ++j) {
                        int col = col0 + j * 16 + l15;
                        float o = fmaxf(acc[i][j][r] + bv2[j], 0.f);
                        out[(long)(col >> 5) * PLANE_ELEMS + (long)grow * 32 + (col & 31)] = f2bf(o);
                    }
                }
        } else {
            float pacc[2];
            #pragma unroll
            for (int j = 0; j < 2; ++j) pacc[j] = 0.f;
            int cur = -1;
            #pragma unroll
            for (int i = 0; i < 4; ++i) {
                #pragma unroll
                for (int r = 0; r < 4; ++r) {
                    int row = row0 + i * 16 + quad * 4 + r;
                    if (row >= M) continue;
                    int g = batch[row];
                    if (g != cur) {
                        if (cur >= 0) {
                            #pragma unroll
                            for (int j = 0; j < 2; ++j)
                                atomicAdd(&sums[(long)cur * 256 + col0 + j * 16 + l15], pacc[j]);
                        }
                        cur = g;
                        #pragma unroll
                        for (int j = 0; j < 2; ++j) pacc[j] = 0.f;
                    }
                    #pragma unroll
                    for (int j = 0; j < 2; ++j)
                        pacc[j] += fmaxf(acc[i][j][r] + bv2[j], 0.f);
                }
            }
            if (cur >= 0) {
                #pragma unroll
                for (int j = 0; j < 2; ++j)
                    atomicAdd(&sums[(long)cur * 256 + col0 + j * 16 + l15], pacc[j]);
            }
        }
    }
}

// ===========================================================================
// Head MLP (fp32): one block per graph; count via binary search on batch.
// ===========================================================================
__global__ __launch_bounds__(256) void final_mlp_kernel(
    const float* __restrict__ sums, const int* __restrict__ batch,
    const float* __restrict__ w1, const float* __restrict__ b1,
    const float* __restrict__ w2, const float* __restrict__ b2,
    float* __restrict__ out) {
    __shared__ float row[HID];
    __shared__ float hid[HID];
    __shared__ int cntS;
    int g = blockIdx.x;
    int t = threadIdx.x;
    if (t == 0) {
        int lo = 0, hi = N_NODES;
        while (lo < hi) { int m = (lo + hi) >> 1; if (batch[m] < g) lo = m + 1; else hi = m; }
        int lo2 = lo, hi2 = N_NODES;
        while (lo2 < hi2) { int m = (lo2 + hi2) >> 1; if (batch[m] < g + 1) lo2 = m + 1; else hi2 = m; }
        cntS = lo2 - lo;
    }
    __syncthreads();
    float cnt = fmaxf((float)cntS, 1.0f);
    row[t] = sums[(long)g * HID + t] / cnt;
    __syncthreads();
    float acc = b1[t];
    for (int k = 0; k < HID; ++k) acc += row[k] * w1[k * HID + t];
    hid[t] = fmaxf(acc, 0.f);
    __syncthreads();
    if (t < OUT_C) {
        float o = b2[t];
        for (int k = 0; k < HID; ++k) o += hid[k] * w2[k * OUT_C + t];
        out[(long)g * OUT_C + t] = o;
    }
}

// ---------------------------------------------------------------------------
extern "C" void kernel_launch(void* const* d_in, const int* in_sizes, int n_in,
                              void* d_out, int out_size, void* d_ws, size_t ws_size,
                              hipStream_t stream) {
    const float* x     = (const float*)d_in[0];
    const int*   ei    = (const int*)d_in[1];
    const int*   batch = (const int*)d_in[2];
    const int*   src   = ei;
    const int*   dst   = ei + N_EDGES;

    const float* c_w1[3] = { (const float*)d_in[3],  (const float*)d_in[7],  (const float*)d_in[11] };
    const float* c_b1[3] = { (const float*)d_in[4],  (const float*)d_in[8],  (const float*)d_in[12] };
    const float* c_w2[3] = { (const float*)d_in[5],  (const float*)d_in[9],  (const float*)d_in[13] };
    const float* c_b2[3] = { (const float*)d_in[6],  (const float*)d_in[10], (const float*)d_in[14] };
    const float* out_w1 = (const float*)d_in[15];
    const float* out_b1 = (const float*)d_in[16];
    const float* out_w2 = (const float*)d_in[17];
    const float* out_b2 = (const float*)d_in[18];

    // ---- Workspace layout (16B aligned) ----
    char* p = (char*)d_ws;
    auto alloc = [&](size_t bytes) {
        char* r = p;
        p += (bytes + 15) & ~(size_t)15;
        return r;
    };
    ushort* xbf  = (ushort*)alloc((size_t)N_NODES * IN_C * 2);   // planar [4][N][32]
    ushort* bufA = (ushort*)alloc((size_t)N_NODES * HID * 2);    // planar [8][N][32]
    ushort* bufB = (ushort*)alloc((size_t)N_NODES * HID * 2);    // row-major agg output
    ushort* wt[6];
    wt[0] = (ushort*)alloc((size_t)IN_C * HID * 2);
    for (int i = 1; i < 6; ++i) wt[i] = (ushort*)alloc((size_t)HID * HID * 2);
    float* sums   = (float*)alloc((size_t)N_GRAPHS * HID * 4);
    int* deg       = (int*)alloc((size_t)N_NODES * 4);
    int* rowptr    = (int*)alloc((size_t)(N_NODES + 1) * 4);
    int* blockSums = (int*)alloc(256 * 4);
    ushort* rank16 = (ushort*)alloc((size_t)N_EDGES * 2);
    uint* pack     = (uint*)alloc((size_t)N_EDGES * 4);
    ushort* srcSorted = (ushort*)alloc((size_t)N_EDGES * 2);     // USHORT indices

    const int nb = (N_NODES + 255) / 256;

    // ---- Prep: casts + zeroing ----
    {
        PrepArgs a;
        a.x = x;
        a.xbf = xbf;
        a.deg = deg;
        a.sums = sums;
        prep_kernel<<<2048, 256, 0, stream>>>(a);
    }
    // ---- Coalesced weight transposes (352 tiles of 32x32) ----
    {
        TransArgs ta;
        ta.w[0] = c_w1[0]; ta.w[1] = c_w2[0];
        ta.w[2] = c_w1[1]; ta.w[3] = c_w2[1];
        ta.w[4] = c_w1[2]; ta.w[5] = c_w2[2];
        for (int i = 0; i < 6; ++i) ta.wt[i] = wt[i];
        transpose_weights<<<352, 256, 0, stream>>>(ta);
    }

    // ---- Build CSR by dst: deg+rank+pack -> scan -> sharded scatter ----
    deg_rank_kernel<<<(N_EDGES + 255) / 256, 256, 0, stream>>>(src, dst, deg, rank16, pack);
    scan_block<<<nb, 256, 0, stream>>>(deg, rowptr, blockSums);
    add_offsets_fused<<<nb, 256, 0, stream>>>(rowptr, blockSums, rowptr, nb);
    {
        const int chunks = (N_EDGES + EDGES_PER_BLK - 1) / EDGES_PER_BLK;  // 391
        scatter_edges_sharded<<<chunks * NSHARD, 256, 0, stream>>>(pack, rank16, rowptr, srcSorted);
    }

    const int nodeBlks = (N_NODES + 63) / 64;        // 782 (even, needed for PER=2)
    const int aggX128  = nodeBlks * (IN_C / 32);     // 3128
    const int aggX256  = nodeBlks * (HID / 32);      // 6256
    const int NPERS    = 256;                        // persistent MLP grid (1/CU)

    // ---- Layer 0 (C_in = 128) ----
    gin_aggregate_planar<IN_C><<<aggX128, 256, 0, stream>>>(xbf, rowptr, srcSorted, bufB);
    gin_mlp_persist<IN_C, false><<<NPERS, 512, 0, stream>>>(bufB, wt[0], c_b1[0], wt[1], c_b2[0],
                                                            bufA, batch, sums, N_NODES, nodeBlks, NPERS);

    // ---- Layer 1 (C = 256) ----
    gin_aggregate_planar<HID><<<aggX256, 256, 0, stream>>>(bufA, rowptr, srcSorted, bufB);
    gin_mlp_persist<HID, false><<<NPERS, 512, 0, stream>>>(bufB, wt[2], c_b1[1], wt[3], c_b2[1],
                                                           bufA, batch, sums, N_NODES, nodeBlks, NPERS);

    // ---- Layer 2 (C = 256) with fused global mean-pool accumulation ----
    gin_aggregate_planar<HID><<<aggX256, 256, 0, stream>>>(bufA, rowptr, srcSorted, bufB);
    gin_mlp_persist<HID, true><<<NPERS, 512, 0, stream>>>(bufB, wt[4], c_b1[2], wt[5], c_b2[2],
                                                          bufA, batch, sums, N_NODES, nodeBlks, NPERS);

    // ---- Head MLP ----
    final_mlp_kernel<<<N_GRAPHS, 256, 0, stream>>>(sums, batch, out_w1, out_b1,
                                                   out_w2, out_b2, (float*)d_out);
}